// Round 8
// baseline (16320.461 us; speedup 1.0000x reference)
//
#include <hip/hip_runtime.h>
#include <stdint.h>

#define H_  128
#define L_  512
#define B_  512
#define A_  16
#define G3_ 384

// ---------------- workspace layout (bytes) ----------------
#define OFF_M1    0          // f16 [384][128]  enc: Wih@enc_emb_W
#define OFF_WHHE  98304      // f16 [384][128]  enc_Whh
#define OFF_WB    196608     // f16 [512][128]  attn_W[:,128:]
#define OFF_WIH   327680     // f16 [384][128]  dec_Wih
#define OFF_WHH   425984     // f16 [384][128]  dec_Whh
#define OFF_WC2   524288     // f16 [128][128]  comb_W[:,128:]
#define OFF_PA    557056     // f16 [512][16]   Wa@dec_emb_W
#define OFF_PC    573440     // f16 [128][16]   Wc1@dec_emb_W
#define OFF_OUTW  577536     // f16 [16][128]
#define OFF_BGI   581632     // f32 [384]  bih + Wih@enc_emb_b
#define OFF_ZB    583168     // f32 [512]  attn_b + Wa@dec_emb_b
#define OFF_OB    585216     // f32 [128]  comb_b + Wc1@dec_emb_b
#define OFF_ENC   585728     // f16 enc_outs INTERLEAVED [c=64][k=128][p=8]
#define OFF_HN    716800     // f32 [512][128]  final encoder hidden

typedef _Float16 f16_t;
typedef __attribute__((ext_vector_type(2))) _Float16 f16x2_t;

__device__ __forceinline__ float dot2f(uint32_t w, uint32_t a, float acc) {
#if __has_builtin(__builtin_amdgcn_fdot2)
  return __builtin_amdgcn_fdot2(__builtin_bit_cast(f16x2_t, w),
                                __builtin_bit_cast(f16x2_t, a), acc, false);
#else
  f16x2_t x = __builtin_bit_cast(f16x2_t, w);
  f16x2_t y = __builtin_bit_cast(f16x2_t, a);
  return acc + (float)x.x * (float)y.x + (float)x.y * (float)y.y;
#endif
}

__device__ __forceinline__ uint32_t pk2(float lo, float hi) {
#if __has_builtin(__builtin_amdgcn_cvt_pkrtz)
  return __builtin_bit_cast(uint32_t, __builtin_amdgcn_cvt_pkrtz(lo, hi));
#else
  f16x2_t v; v.x = (_Float16)lo; v.y = (_Float16)hi;
  return __builtin_bit_cast(uint32_t, v);
#endif
}

__device__ __forceinline__ float sigm(float x) { return 1.f / (1.f + __expf(-x)); }
__device__ __forceinline__ float tanh_s(float t) { float ex = __expf(2.f * t); return 1.f - 2.f / (ex + 1.f); }

#define LDS4(arr, idx) (*(const uint4*)&(arr)[(idx)])

// =====================================================================
// prep: weight folds + f16 conversions (unchanged)
// =====================================================================
__global__ void prep_kernel(const float* __restrict__ enc_emb_W, const float* __restrict__ enc_emb_b,
                            const float* __restrict__ enc_Wih, const float* __restrict__ enc_bih,
                            const float* __restrict__ dec_emb_W, const float* __restrict__ dec_emb_b,
                            const float* __restrict__ attn_W, const float* __restrict__ attn_b,
                            const float* __restrict__ comb_W, const float* __restrict__ comb_b,
                            const float* __restrict__ dec_Wih, const float* __restrict__ dec_Whh,
                            const float* __restrict__ enc_Whh, const float* __restrict__ out_W,
                            char* __restrict__ ws) {
  int t = blockIdx.x * 256 + threadIdx.x;
  if (t < 49152) {                       // M1 [384][128]
    int n = t >> 7, d = t & 127; float acc = 0.f;
    for (int h = 0; h < 128; ++h) acc += enc_Wih[n*128+h] * enc_emb_W[h*128+d];
    ((f16_t*)(ws+OFF_M1))[t] = (f16_t)acc; return;
  } t -= 49152;
  if (t < 384) {                         // bias_gi
    float acc = enc_bih[t];
    for (int h = 0; h < 128; ++h) acc += enc_Wih[t*128+h] * enc_emb_b[h];
    ((float*)(ws+OFF_BGI))[t] = acc; return;
  } t -= 384;
  if (t < 8192) {                        // P_a [512][16]
    int l = t >> 4, a = t & 15; float acc = 0.f;
    for (int k = 0; k < 128; ++k) acc += attn_W[l*256+k] * dec_emb_W[k*16+a];
    ((f16_t*)(ws+OFF_PA))[t] = (f16_t)acc; return;
  } t -= 8192;
  if (t < 512) {                         // zbias [512]
    float acc = attn_b[t];
    for (int k = 0; k < 128; ++k) acc += attn_W[t*256+k] * dec_emb_b[k];
    ((float*)(ws+OFF_ZB))[t] = acc; return;
  } t -= 512;
  if (t < 2048) {                        // P_c [128][16]
    int j = t >> 4, a = t & 15; float acc = 0.f;
    for (int k = 0; k < 128; ++k) acc += comb_W[j*256+k] * dec_emb_W[k*16+a];
    ((f16_t*)(ws+OFF_PC))[t] = (f16_t)acc; return;
  } t -= 2048;
  if (t < 128) {                         // obias [128]
    float acc = comb_b[t];
    for (int k = 0; k < 128; ++k) acc += comb_W[t*256+k] * dec_emb_b[k];
    ((float*)(ws+OFF_OB))[t] = acc; return;
  } t -= 128;
  if (t < 65536) {                       // Wb [512][128]
    int l = t >> 7, k = t & 127;
    ((f16_t*)(ws+OFF_WB))[t] = (f16_t)attn_W[l*256+128+k]; return;
  } t -= 65536;
  if (t < 49152) { ((f16_t*)(ws+OFF_WHHE))[t] = (f16_t)enc_Whh[t]; return; } t -= 49152;
  if (t < 49152) { ((f16_t*)(ws+OFF_WIH))[t]  = (f16_t)dec_Wih[t]; return; } t -= 49152;
  if (t < 49152) { ((f16_t*)(ws+OFF_WHH))[t]  = (f16_t)dec_Whh[t]; return; } t -= 49152;
  if (t < 16384) {                       // Wc2 [128][128]
    int j = t >> 7, k = t & 127;
    ((f16_t*)(ws+OFF_WC2))[t] = (f16_t)comb_W[j*256+128+k]; return;
  } t -= 16384;
  if (t < 2048) { ((f16_t*)(ws+OFF_OUTW))[t] = (f16_t)out_W[t]; return; }
}

// =====================================================================
// encoder: 256 blocks x 512 thr, rows (2b, 2b+1), 512 steps
// (round-6 proven); enc_outs written INTERLEAVED for dec global reads
// =====================================================================
__global__ __launch_bounds__(512, 1) void enc_kernel(const float* __restrict__ obs,
                                                     const float* __restrict__ enc_bhh,
                                                     char* __restrict__ ws) {
  __shared__ __align__(16) uint32_t obspk[2][64];
  __shared__ __align__(16) uint32_t hpk[2][64];
  __shared__ __align__(16) float    gi_s[2][G3_];
  __shared__ __align__(16) float    gh_s[2][G3_];
  __shared__ float bgi_s[G3_], bhh_s[G3_];

  const int tid = threadIdx.x, bid = blockIdx.x;
  const uint32_t* M1u  = (const uint32_t*)(ws + OFF_M1);
  const uint32_t* WHu  = (const uint32_t*)(ws + OFF_WHHE);
  const float*    bgi  = (const float*)(ws + OFF_BGI);
  f16_t* encw = (f16_t*)(ws + OFF_ENC);
  float* hN   = (float*)(ws + OFF_HN);

  uint32_t m1r[64], whr[64];
  if (tid < G3_) {
    const uint4* p1 = (const uint4*)(M1u + tid*64);
    const uint4* p2 = (const uint4*)(WHu + tid*64);
#pragma unroll
    for (int q = 0; q < 16; ++q) {
      uint4 v = p1[q]; m1r[q*4]=v.x; m1r[q*4+1]=v.y; m1r[q*4+2]=v.z; m1r[q*4+3]=v.w;
      uint4 w = p2[q]; whr[q*4]=w.x; whr[q*4+1]=w.y; whr[q*4+2]=w.z; whr[q*4+3]=w.w;
    }
    bgi_s[tid] = bgi[tid]; bhh_s[tid] = enc_bhh[tid];
  }

  const int r = tid >> 7, jj = tid & 127;   // valid for tid<256
  const size_t rowbase = (size_t)(2*bid + r) * L_ * H_ + jj;
  float hreg = 0.f;
  float oA = 0.f;
  if (tid < 256) {
    float o0 = obs[rowbase + 0*H_];
    float op = __shfl_xor(o0, 1);
    if (!(jj & 1)) obspk[r][jj >> 1] = pk2(o0, op);
    oA = obs[rowbase + 1*H_];
  }
  if (tid < 128) hpk[tid>>6][tid&63] = 0u;
  __syncthreads();

#pragma unroll 1
  for (int t = 0; t < L_; ++t) {
    float oB = 0.f;
    if (tid < 256) {
      int tn = (t+2 < L_) ? t+2 : L_-1;
      oB = obs[rowbase + (size_t)tn*H_];
    }
    if (tid < G3_) {
      float g0 = bgi_s[tid], g1 = g0, ga = 0.f, gb = 0.f;
      float e0 = bhh_s[tid], e1 = e0, ea = 0.f, eb = 0.f;
#pragma unroll
      for (int c = 0; c < 16; ++c) {
        uint4 o0 = LDS4(obspk[0], c*4); uint4 o1 = LDS4(obspk[1], c*4);
        uint4 h0 = LDS4(hpk[0],  c*4);  uint4 h1 = LDS4(hpk[1],  c*4);
        g0 = dot2f(m1r[c*4+0], o0.x, g0); g0 = dot2f(m1r[c*4+1], o0.y, g0);
        ga = dot2f(m1r[c*4+2], o0.z, ga); ga = dot2f(m1r[c*4+3], o0.w, ga);
        g1 = dot2f(m1r[c*4+0], o1.x, g1); g1 = dot2f(m1r[c*4+1], o1.y, g1);
        gb = dot2f(m1r[c*4+2], o1.z, gb); gb = dot2f(m1r[c*4+3], o1.w, gb);
        e0 = dot2f(whr[c*4+0], h0.x, e0); e0 = dot2f(whr[c*4+1], h0.y, e0);
        ea = dot2f(whr[c*4+2], h0.z, ea); ea = dot2f(whr[c*4+3], h0.w, ea);
        e1 = dot2f(whr[c*4+0], h1.x, e1); e1 = dot2f(whr[c*4+1], h1.y, e1);
        eb = dot2f(whr[c*4+2], h1.z, eb); eb = dot2f(whr[c*4+3], h1.w, eb);
      }
      gi_s[0][tid] = g0+ga; gi_s[1][tid] = g1+gb;
      gh_s[0][tid] = e0+ea; gh_s[1][tid] = e1+eb;
    }
    __syncthreads();
    if (tid < 256) {
      float ir = gi_s[r][jj], iz = gi_s[r][jj+128], in_ = gi_s[r][jj+256];
      float hr = gh_s[r][jj], hz = gh_s[r][jj+128], hn = gh_s[r][jj+256];
      float rg = sigm(ir + hr);
      float zg = sigm(iz + hz);
      float nn = tanh_s(in_ + rg * hn);
      float h2 = (1.f - zg) * nn + zg * hreg;
      hreg = h2;
      float hp = __shfl_xor(h2, 1);
      float op = __shfl_xor(oA, 1);
      if (!(jj & 1)) {
        hpk[r][jj >> 1] = pk2(h2, hp);
        obspk[r][jj >> 1] = pk2(oA, op);
      }
      // interleaved enc_outs: [c=t>>3][k=jj][p=t&7]
      if (bid == 0 && r == 0) encw[(((t >> 3) * 128 + jj) << 3) + (t & 7)] = (f16_t)h2;
      oA = oB;
    }
    __syncthreads();
  }
  if (tid < 256) hN[(2*bid + r)*H_ + jj] = hreg;
}

// =====================================================================
// decoder: 512 blocks x 512 thr, ONE row per block, 512 steps.
// enc_outs read from GLOBAL (L2-resident, interleaved) -> LDS ~30KB ->
// 2 blocks/CU (16 waves/CU). Weights register-resident ((512,1) proven).
// 5 barriers/step: gates+output+logsoftmax fused in wave0 via in-wave
// LDS ordering (s_waitcnt lgkmcnt(0), no barrier).
// =====================================================================
__global__ __launch_bounds__(512, 1) void dec_kernel(const float* __restrict__ dec_bih,
                                                     const float* __restrict__ dec_bhh,
                                                     const float* __restrict__ out_b,
                                                     char* __restrict__ ws,
                                                     float* __restrict__ dout) {
  __shared__ __align__(16) uint32_t paL[4096];   // 16KB  P_a [q][l]
  __shared__ __align__(16) uint32_t pcL[1024];   // 4KB   P_c [q][j]
  __shared__ __align__(16) uint32_t owL[1024];   // 4KB   out_W [(c*16+a)*4+q]
  __shared__ __align__(16) uint32_t awpk[272];   // 1088B raw exp pairs (+4w pad/64)
  __shared__ __align__(16) uint32_t aplpk[64];   // 256B
  __shared__ __align__(16) float    gi_s[G3_];   // 1536B
  __shared__ __align__(16) float    gh_s[G3_];   // 1536B
  __shared__ __align__(16) uint32_t opk[64];     // 256B
  __shared__ __align__(16) uint32_t hpk[64];     // 256B
  __shared__ __align__(16) uint32_t inppk[8];    // 32B
  __shared__ float reds[8];                      // 32B
  // total ~29.4 KB -> 2 blocks/CU

  const int tid = threadIdx.x, bid = blockIdx.x;
  const uint32_t* WBu  = (const uint32_t*)(ws + OFF_WB);
  const uint32_t* WIu  = (const uint32_t*)(ws + OFF_WIH);
  const uint32_t* WHu  = (const uint32_t*)(ws + OFF_WHH);
  const uint32_t* WCu  = (const uint32_t*)(ws + OFF_WC2);
  const uint32_t* PAu  = (const uint32_t*)(ws + OFF_PA);
  const uint32_t* PCu  = (const uint32_t*)(ws + OFF_PC);
  const uint32_t* OWu  = (const uint32_t*)(ws + OFF_OUTW);
  const uint32_t* encG = (const uint32_t*)(ws + OFF_ENC);
  const float*    zb   = (const float*)(ws + OFF_ZB);
  const float*    obg  = (const float*)(ws + OFF_OB);
  const float*    hN   = (const float*)(ws + OFF_HN);

  // ---- register-stationary weights ----
  uint32_t wb[64], wA[64], wB[64];
  {
    const uint4* p = (const uint4*)(WBu + tid*64);
#pragma unroll
    for (int q = 0; q < 16; ++q) { uint4 v = p[q]; wb[q*4]=v.x; wb[q*4+1]=v.y; wb[q*4+2]=v.z; wb[q*4+3]=v.w; }
  }
  if (tid < G3_) {
    const uint4* p = (const uint4*)(WIu + tid*64);
    const uint4* p2 = (const uint4*)(WHu + tid*64);
#pragma unroll
    for (int q = 0; q < 16; ++q) {
      uint4 v = p[q];  wA[q*4]=v.x; wA[q*4+1]=v.y; wA[q*4+2]=v.z; wA[q*4+3]=v.w;
      uint4 w = p2[q]; wB[q*4]=w.x; wB[q*4+1]=w.y; wB[q*4+2]=w.z; wB[q*4+3]=w.w;
    }
  } else {
    const uint4* p = (const uint4*)(WCu + (tid-384)*64);
#pragma unroll
    for (int q = 0; q < 16; ++q) {
      uint4 v = p[q]; wA[q*4]=v.x; wA[q*4+1]=v.y; wA[q*4+2]=v.z; wA[q*4+3]=v.w;
    }
  }

  // ---- stage P_a [q][l], P_c [q][j], out_W into LDS ----
  for (int idx = tid; idx < 4096; idx += 512) {
    int q = idx >> 9, l = idx & 511;
    paL[idx] = PAu[l*8 + q];
  }
  for (int idx = tid; idx < 1024; idx += 512) {
    int q = idx >> 7, j = idx & 127;
    pcL[idx] = PCu[j*8 + q];
    int qq = idx & 3, rest = idx >> 2, a = rest & 15, c = rest >> 4;
    owL[(c*16 + a)*4 + qq] = OWu[a*64 + c*4 + qq];
  }
  const float zbias    = zb[tid];
  const float bih_reg  = (tid < G3_) ? dec_bih[tid] : 0.f;
  const float bhh_reg  = (tid < G3_) ? dec_bhh[tid] : 0.f;
  const float ob_reg   = (tid >= G3_) ? obg[tid - G3_] : 0.f;
  const float outb_reg = (tid < 16) ? out_b[tid] : 0.f;
  if (tid < 8) inppk[tid] = 0u;

  float hx = 0.f, hy = 0.f;               // persistent h (wave0: dims 2*tid, 2*tid+1)
  if (tid < 64) {
    hx = hN[bid*H_ + 2*tid];
    hy = hN[bid*H_ + 2*tid + 1];
    hpk[tid] = pk2(hx, hy);
  }
  const int kI2 = tid >> 2, ch = tid & 3;  // I2 mapping
  __syncthreads();

#pragma unroll 1
  for (int t = 0; t < L_; ++t) {
    // ---------- I1: attn logits z_l (l = tid), raw exp, wave sums ----------
    {
      uint32_t paq[8];
#pragma unroll
      for (int q = 0; q < 8; ++q) paq[q] = paL[q*512 + tid];
      uint4 i0 = LDS4(inppk, 0), i0b = LDS4(inppk, 4);
      float a0 = dot2f(paq[0], i0.x, zbias); a0 = dot2f(paq[1], i0.y, a0);
      a0 = dot2f(paq[2], i0.z, a0);          a0 = dot2f(paq[3], i0.w, a0);
      float b0 = dot2f(paq[4], i0b.x, 0.f);  b0 = dot2f(paq[5], i0b.y, b0);
      b0 = dot2f(paq[6], i0b.z, b0);         b0 = dot2f(paq[7], i0b.w, b0);
#pragma unroll
      for (int c = 0; c < 16; ++c) {
        uint4 h0 = LDS4(hpk, c*4);
        a0 = dot2f(wb[c*4+0], h0.x, a0); a0 = dot2f(wb[c*4+1], h0.y, a0);
        b0 = dot2f(wb[c*4+2], h0.z, b0); b0 = dot2f(wb[c*4+3], h0.w, b0);
      }
      // max-free: |z| <= ~10 << 88, raw expf safe in f32
      float e0 = __expf(a0 + b0);
      float s0 = e0;
#pragma unroll
      for (int off = 32; off; off >>= 1) s0 += __shfl_xor(s0, off);
      if ((tid & 63) == 0) reds[tid >> 6] = s0;
      float ep0 = __shfl_xor(e0, 1);
      int awi = (tid >> 1) + ((tid >> 7) << 2);
      if (!(tid & 1)) awpk[awi] = pk2(e0, ep0);
    }
    __syncthreads();   // S1
    // ---------- I2: applied = aw @ enc_outs (GLOBAL reads, L2-resident) ----------
    {
      float S = reds[0];
#pragma unroll
      for (int i = 1; i < 8; ++i) S += reds[i];
      float is = 1.f / S;
      float acc0 = 0.f, acc1 = 0.f;
#pragma unroll
      for (int cc = 0; cc < 16; ++cc) {
        int c = ch*16 + cc;
        uint4 ev = *(const uint4*)(encG + (size_t)(c*128 + kI2)*4);
        uint4 w  = LDS4(awpk, c*4 + ((c >> 4) << 2));
        acc0 = dot2f(ev.x, w.x, acc0); acc0 = dot2f(ev.y, w.y, acc0);
        acc1 = dot2f(ev.z, w.z, acc1); acc1 = dot2f(ev.w, w.w, acc1);
      }
      float v = (acc0 + acc1) * is;
      v += __shfl_xor(v, 1); v += __shfl_xor(v, 2);   // combine 4 chunks (same k)
      float vp = __shfl_xor(v, 4);                    // partner k+1
      if (!(tid & 7)) aplpk[tid >> 3] = pk2(v, vp);
    }
    __syncthreads();   // S2
    // ---------- I3: {tid>=384: o_j} || {tid<384: gh_n} ----------
    if (tid >= G3_) {
      int j = tid - G3_;
      uint32_t pcq[8];
#pragma unroll
      for (int q = 0; q < 8; ++q) pcq[q] = pcL[q*128 + j];
      uint4 i0 = LDS4(inppk, 0), i0b = LDS4(inppk, 4);
      float o0 = dot2f(pcq[0], i0.x, ob_reg); o0 = dot2f(pcq[1], i0.y, o0);
      o0 = dot2f(pcq[2], i0.z, o0);           o0 = dot2f(pcq[3], i0.w, o0);
      float oa = dot2f(pcq[4], i0b.x, 0.f);   oa = dot2f(pcq[5], i0b.y, oa);
      oa = dot2f(pcq[6], i0b.z, oa);          oa = dot2f(pcq[7], i0b.w, oa);
#pragma unroll
      for (int c = 0; c < 16; ++c) {
        uint4 p0 = LDS4(aplpk, c*4);
        o0 = dot2f(wA[c*4+0], p0.x, o0); o0 = dot2f(wA[c*4+1], p0.y, o0);
        oa = dot2f(wA[c*4+2], p0.z, oa); oa = dot2f(wA[c*4+3], p0.w, oa);
      }
      o0 = fmaxf(o0 + oa, 0.f);
      float px = __shfl_xor(o0, 1);
      if (!(j & 1)) opk[j >> 1] = pk2(o0, px);
    } else {
      float e0g = bhh_reg, ea = 0.f;
#pragma unroll
      for (int c = 0; c < 16; ++c) {
        uint4 h0 = LDS4(hpk, c*4);
        e0g = dot2f(wB[c*4+0], h0.x, e0g); e0g = dot2f(wB[c*4+1], h0.y, e0g);
        ea  = dot2f(wB[c*4+2], h0.z, ea);  ea  = dot2f(wB[c*4+3], h0.w, ea);
      }
      gh_s[tid] = e0g + ea;
    }
    __syncthreads();   // S3
    // ---------- I4: gi = o@Wih^T + bih (tid<384) ----------
    if (tid < G3_) {
      float g0 = bih_reg, ga = 0.f;
#pragma unroll
      for (int c = 0; c < 16; ++c) {
        uint4 o0 = LDS4(opk, c*4);
        g0 = dot2f(wA[c*4+0], o0.x, g0); g0 = dot2f(wA[c*4+1], o0.y, g0);
        ga = dot2f(wA[c*4+2], o0.z, ga); ga = dot2f(wA[c*4+3], o0.w, ga);
      }
      gi_s[tid] = g0 + ga;
    }
    __syncthreads();   // S4
    // ---------- I5 (fused, wave0): gates -> y=h@outW -> log_softmax -> feedback ----------
    if (tid < 64) {
      float2 ir2 = *(const float2*)&gi_s[2*tid];
      float2 iz2 = *(const float2*)&gi_s[128 + 2*tid];
      float2 in2 = *(const float2*)&gi_s[256 + 2*tid];
      float2 hr2 = *(const float2*)&gh_s[2*tid];
      float2 hz2 = *(const float2*)&gh_s[128 + 2*tid];
      float2 hn2 = *(const float2*)&gh_s[256 + 2*tid];
      {
        float rg = sigm(ir2.x + hr2.x);
        float zg = sigm(iz2.x + hz2.x);
        float nn = tanh_s(in2.x + rg * hn2.x);
        hx = (1.f - zg) * nn + zg * hx;
      }
      {
        float rg = sigm(ir2.y + hr2.y);
        float zg = sigm(iz2.y + hz2.y);
        float nn = tanh_s(in2.y + rg * hn2.y);
        hy = (1.f - zg) * nn + zg * hy;
      }
      hpk[tid] = pk2(hx, hy);
      // in-wave LDS write->read ordering (no barrier needed: wave0 only)
      asm volatile("s_waitcnt lgkmcnt(0)" ::: "memory");
      int a = tid & 15, ks = tid >> 4;
      float y = (ks == 0) ? outb_reg : 0.f;
#pragma unroll
      for (int w = 0; w < 4; ++w) {
        int c = ks*4 + w;
        uint4 ww = *(const uint4*)&owL[(c*16 + a)*4];
        uint4 hb = LDS4(hpk, c*4);
        y = dot2f(ww.x, hb.x, y); y = dot2f(ww.y, hb.y, y);
        y = dot2f(ww.z, hb.z, y); y = dot2f(ww.w, hb.w, y);
      }
      y += __shfl_xor(y, 16); y += __shfl_xor(y, 32);
      if (tid < 16) {
        float e = __expf(y);   // |y| small: max-free safe
        float s = e;
#pragma unroll
        for (int off = 8; off; off >>= 1) s += __shfl_xor(s, off);
        float lsf = y - __logf(s);
        if (t == L_-1) dout[bid*A_ + a] = lsf;
        float pr = __shfl_xor(lsf, 1);
        if (!(a & 1)) inppk[a >> 1] = pk2(lsf, pr);
      }
    }
    __syncthreads();   // S5
  }
}

// =====================================================================
extern "C" void kernel_launch(void* const* d_in, const int* in_sizes, int n_in,
                              void* d_out, int out_size, void* d_ws, size_t ws_size,
                              hipStream_t stream) {
  (void)in_sizes; (void)n_in; (void)out_size; (void)ws_size;
  const float* obs       = (const float*)d_in[0];
  const float* enc_emb_W = (const float*)d_in[1];
  const float* enc_emb_b = (const float*)d_in[2];
  const float* enc_Wih   = (const float*)d_in[3];
  const float* enc_Whh   = (const float*)d_in[4];
  const float* enc_bih   = (const float*)d_in[5];
  const float* enc_bhh   = (const float*)d_in[6];
  const float* dec_emb_W = (const float*)d_in[7];
  const float* dec_emb_b = (const float*)d_in[8];
  const float* attn_W    = (const float*)d_in[9];
  const float* attn_b    = (const float*)d_in[10];
  const float* comb_W    = (const float*)d_in[11];
  const float* comb_b    = (const float*)d_in[12];
  const float* dec_Wih   = (const float*)d_in[13];
  const float* dec_Whh   = (const float*)d_in[14];
  const float* dec_bih   = (const float*)d_in[15];
  const float* dec_bhh   = (const float*)d_in[16];
  const float* out_W     = (const float*)d_in[17];
  const float* out_b     = (const float*)d_in[18];
  char* ws = (char*)d_ws;

  hipLaunchKernelGGL(prep_kernel, dim3(1140), dim3(256), 0, stream,
                     enc_emb_W, enc_emb_b, enc_Wih, enc_bih, dec_emb_W, dec_emb_b,
                     attn_W, attn_b, comb_W, comb_b, dec_Wih, dec_Whh, enc_Whh, out_W, ws);
  hipLaunchKernelGGL(enc_kernel, dim3(256), dim3(512), 0, stream, obs, enc_bhh, ws);
  hipLaunchKernelGGL(dec_kernel, dim3(512), dim3(512), 0, stream,
                     dec_bih, dec_bhh, out_b, ws, (float*)d_out);
}

// Round 9
// 5435.830 us; speedup vs baseline: 3.0024x; 3.0024x over previous
//
#include <hip/hip_runtime.h>
#include <stdint.h>

#define H_  128
#define L_  512
#define B_  512
#define A_  16
#define G3_ 384

// ---------------- workspace layout (bytes) ----------------
#define OFF_M1    0          // f16 [384][128]  enc: Wih@enc_emb_W
#define OFF_WHHE  98304      // f16 [384][128]  enc_Whh
#define OFF_WB    196608     // f16 [512][128]  attn_W[:,128:]
#define OFF_WIH   327680     // f16 [384][128]  dec_Wih
#define OFF_WHH   425984     // f16 [384][128]  dec_Whh
#define OFF_WC2   524288     // f16 [128][128]  comb_W[:,128:]
#define OFF_PA    557056     // f16 [512][16]   Wa@dec_emb_W
#define OFF_PC    573440     // f16 [128][16]   Wc1@dec_emb_W
#define OFF_OUTW  577536     // f16 [16][128]
#define OFF_BGI   581632     // f32 [384]  bih + Wih@enc_emb_b
#define OFF_ZB    583168     // f32 [512]  attn_b + Wa@dec_emb_b
#define OFF_OB    585216     // f32 [128]  comb_b + Wc1@dec_emb_b
#define OFF_ENC   585728     // f16 [512][128]  enc_outs
#define OFF_HN    716800     // f32 [512][128]  final encoder hidden

typedef _Float16 f16_t;
typedef __attribute__((ext_vector_type(2))) _Float16 f16x2_t;

__device__ __forceinline__ float dot2f(uint32_t w, uint32_t a, float acc) {
#if __has_builtin(__builtin_amdgcn_fdot2)
  return __builtin_amdgcn_fdot2(__builtin_bit_cast(f16x2_t, w),
                                __builtin_bit_cast(f16x2_t, a), acc, false);
#else
  f16x2_t x = __builtin_bit_cast(f16x2_t, w);
  f16x2_t y = __builtin_bit_cast(f16x2_t, a);
  return acc + (float)x.x * (float)y.x + (float)x.y * (float)y.y;
#endif
}

__device__ __forceinline__ uint32_t pk2(float lo, float hi) {
#if __has_builtin(__builtin_amdgcn_cvt_pkrtz)
  return __builtin_bit_cast(uint32_t, __builtin_amdgcn_cvt_pkrtz(lo, hi));
#else
  f16x2_t v; v.x = (_Float16)lo; v.y = (_Float16)hi;
  return __builtin_bit_cast(uint32_t, v);
#endif
}

__device__ __forceinline__ float sigm(float x) { return 1.f / (1.f + __expf(-x)); }
__device__ __forceinline__ float tanh_s(float t) { float ex = __expf(2.f * t); return 1.f - 2.f / (ex + 1.f); }
__device__ __forceinline__ float gru1(float ir, float iz, float in_, float hr, float hz, float hn, float h) {
  float rg = sigm(ir + hr);
  float zg = sigm(iz + hz);
  float nn = tanh_s(in_ + rg * hn);
  return (1.f - zg) * nn + zg * h;
}

#define LDS4(arr, idx) (*(const uint4*)&(arr)[(idx)])

// =====================================================================
// prep: weight folds + f16 conversions (unchanged)
// =====================================================================
__global__ void prep_kernel(const float* __restrict__ enc_emb_W, const float* __restrict__ enc_emb_b,
                            const float* __restrict__ enc_Wih, const float* __restrict__ enc_bih,
                            const float* __restrict__ dec_emb_W, const float* __restrict__ dec_emb_b,
                            const float* __restrict__ attn_W, const float* __restrict__ attn_b,
                            const float* __restrict__ comb_W, const float* __restrict__ comb_b,
                            const float* __restrict__ dec_Wih, const float* __restrict__ dec_Whh,
                            const float* __restrict__ enc_Whh, const float* __restrict__ out_W,
                            char* __restrict__ ws) {
  int t = blockIdx.x * 256 + threadIdx.x;
  if (t < 49152) {                       // M1 [384][128]
    int n = t >> 7, d = t & 127; float acc = 0.f;
    for (int h = 0; h < 128; ++h) acc += enc_Wih[n*128+h] * enc_emb_W[h*128+d];
    ((f16_t*)(ws+OFF_M1))[t] = (f16_t)acc; return;
  } t -= 49152;
  if (t < 384) {                         // bias_gi
    float acc = enc_bih[t];
    for (int h = 0; h < 128; ++h) acc += enc_Wih[t*128+h] * enc_emb_b[h];
    ((float*)(ws+OFF_BGI))[t] = acc; return;
  } t -= 384;
  if (t < 8192) {                        // P_a [512][16]
    int l = t >> 4, a = t & 15; float acc = 0.f;
    for (int k = 0; k < 128; ++k) acc += attn_W[l*256+k] * dec_emb_W[k*16+a];
    ((f16_t*)(ws+OFF_PA))[t] = (f16_t)acc; return;
  } t -= 8192;
  if (t < 512) {                         // zbias [512]
    float acc = attn_b[t];
    for (int k = 0; k < 128; ++k) acc += attn_W[t*256+k] * dec_emb_b[k];
    ((float*)(ws+OFF_ZB))[t] = acc; return;
  } t -= 512;
  if (t < 2048) {                        // P_c [128][16]
    int j = t >> 4, a = t & 15; float acc = 0.f;
    for (int k = 0; k < 128; ++k) acc += comb_W[j*256+k] * dec_emb_W[k*16+a];
    ((f16_t*)(ws+OFF_PC))[t] = (f16_t)acc; return;
  } t -= 2048;
  if (t < 128) {                         // obias [128]
    float acc = comb_b[t];
    for (int k = 0; k < 128; ++k) acc += comb_W[t*256+k] * dec_emb_b[k];
    ((float*)(ws+OFF_OB))[t] = acc; return;
  } t -= 128;
  if (t < 65536) {                       // Wb [512][128]
    int l = t >> 7, k = t & 127;
    ((f16_t*)(ws+OFF_WB))[t] = (f16_t)attn_W[l*256+128+k]; return;
  } t -= 65536;
  if (t < 49152) { ((f16_t*)(ws+OFF_WHHE))[t] = (f16_t)enc_Whh[t]; return; } t -= 49152;
  if (t < 49152) { ((f16_t*)(ws+OFF_WIH))[t]  = (f16_t)dec_Wih[t]; return; } t -= 49152;
  if (t < 49152) { ((f16_t*)(ws+OFF_WHH))[t]  = (f16_t)dec_Whh[t]; return; } t -= 49152;
  if (t < 16384) {                       // Wc2 [128][128]
    int j = t >> 7, k = t & 127;
    ((f16_t*)(ws+OFF_WC2))[t] = (f16_t)comb_W[j*256+128+k]; return;
  } t -= 16384;
  if (t < 2048) { ((f16_t*)(ws+OFF_OUTW))[t] = (f16_t)out_W[t]; return; }
}

// =====================================================================
// encoder: 256 blocks x 512 thr, rows (2b, 2b+1), 512 steps
// (round-6 proven config)
// =====================================================================
__global__ __launch_bounds__(512, 1) void enc_kernel(const float* __restrict__ obs,
                                                     const float* __restrict__ enc_bhh,
                                                     char* __restrict__ ws) {
  __shared__ __align__(16) uint32_t obspk[2][64];
  __shared__ __align__(16) uint32_t hpk[2][64];
  __shared__ __align__(16) float    gi_s[2][G3_];
  __shared__ __align__(16) float    gh_s[2][G3_];
  __shared__ float bgi_s[G3_], bhh_s[G3_];

  const int tid = threadIdx.x, bid = blockIdx.x;
  const uint32_t* M1u  = (const uint32_t*)(ws + OFF_M1);
  const uint32_t* WHu  = (const uint32_t*)(ws + OFF_WHHE);
  const float*    bgi  = (const float*)(ws + OFF_BGI);
  f16_t* encw = (f16_t*)(ws + OFF_ENC);
  float* hN   = (float*)(ws + OFF_HN);

  uint32_t m1r[64], whr[64];
  if (tid < G3_) {
    const uint4* p1 = (const uint4*)(M1u + tid*64);
    const uint4* p2 = (const uint4*)(WHu + tid*64);
#pragma unroll
    for (int q = 0; q < 16; ++q) {
      uint4 v = p1[q]; m1r[q*4]=v.x; m1r[q*4+1]=v.y; m1r[q*4+2]=v.z; m1r[q*4+3]=v.w;
      uint4 w = p2[q]; whr[q*4]=w.x; whr[q*4+1]=w.y; whr[q*4+2]=w.z; whr[q*4+3]=w.w;
    }
    bgi_s[tid] = bgi[tid]; bhh_s[tid] = enc_bhh[tid];
  }

  const int r = tid >> 7, jj = tid & 127;   // valid for tid<256
  const size_t rowbase = (size_t)(2*bid + r) * L_ * H_ + jj;
  float hreg = 0.f;
  float oA = 0.f;
  if (tid < 256) {
    float o0 = obs[rowbase + 0*H_];
    float op = __shfl_xor(o0, 1);
    if (!(jj & 1)) obspk[r][jj >> 1] = pk2(o0, op);
    oA = obs[rowbase + 1*H_];
  }
  if (tid < 128) hpk[tid>>6][tid&63] = 0u;
  __syncthreads();

#pragma unroll 1
  for (int t = 0; t < L_; ++t) {
    float oB = 0.f;
    if (tid < 256) {
      int tn = (t+2 < L_) ? t+2 : L_-1;
      oB = obs[rowbase + (size_t)tn*H_];
    }
    if (tid < G3_) {
      float g0 = bgi_s[tid], g1 = g0, ga = 0.f, gb = 0.f;
      float e0 = bhh_s[tid], e1 = e0, ea = 0.f, eb = 0.f;
#pragma unroll
      for (int c = 0; c < 16; ++c) {
        uint4 o0 = LDS4(obspk[0], c*4); uint4 o1 = LDS4(obspk[1], c*4);
        uint4 h0 = LDS4(hpk[0],  c*4);  uint4 h1 = LDS4(hpk[1],  c*4);
        g0 = dot2f(m1r[c*4+0], o0.x, g0); g0 = dot2f(m1r[c*4+1], o0.y, g0);
        ga = dot2f(m1r[c*4+2], o0.z, ga); ga = dot2f(m1r[c*4+3], o0.w, ga);
        g1 = dot2f(m1r[c*4+0], o1.x, g1); g1 = dot2f(m1r[c*4+1], o1.y, g1);
        gb = dot2f(m1r[c*4+2], o1.z, gb); gb = dot2f(m1r[c*4+3], o1.w, gb);
        e0 = dot2f(whr[c*4+0], h0.x, e0); e0 = dot2f(whr[c*4+1], h0.y, e0);
        ea = dot2f(whr[c*4+2], h0.z, ea); ea = dot2f(whr[c*4+3], h0.w, ea);
        e1 = dot2f(whr[c*4+0], h1.x, e1); e1 = dot2f(whr[c*4+1], h1.y, e1);
        eb = dot2f(whr[c*4+2], h1.z, eb); eb = dot2f(whr[c*4+3], h1.w, eb);
      }
      gi_s[0][tid] = g0+ga; gi_s[1][tid] = g1+gb;
      gh_s[0][tid] = e0+ea; gh_s[1][tid] = e1+eb;
    }
    __syncthreads();
    if (tid < 256) {
      float ir = gi_s[r][jj], iz = gi_s[r][jj+128], in_ = gi_s[r][jj+256];
      float hr = gh_s[r][jj], hz = gh_s[r][jj+128], hn = gh_s[r][jj+256];
      float h2 = gru1(ir, iz, in_, hr, hz, hn, hreg);
      hreg = h2;
      float hp = __shfl_xor(h2, 1);
      float op = __shfl_xor(oA, 1);
      if (!(jj & 1)) {
        hpk[r][jj >> 1] = pk2(h2, hp);
        obspk[r][jj >> 1] = pk2(oA, op);
      }
      if (bid == 0 && r == 0) encw[t*H_ + jj] = (f16_t)h2;
      oA = oB;
    }
    __syncthreads();
  }
  if (tid < 256) hN[(2*bid + r)*H_ + jj] = hreg;
}

// =====================================================================
// decoder: 256 blocks x 512 thr, rows (2b, 2b+1), 512 steps.
// Round-6 proven base (encI in LDS, (512,1), weights in regs/AGPR),
// + max-free softmax, + fused gates/output/log-softmax wave0 phase.
// 5 barriers/step; zero in-loop global traffic.
// =====================================================================
__global__ __launch_bounds__(512, 1) void dec_kernel(const float* __restrict__ dec_bih,
                                                     const float* __restrict__ dec_bhh,
                                                     const float* __restrict__ out_b,
                                                     char* __restrict__ ws,
                                                     float* __restrict__ dout) {
  __shared__ __align__(16) uint32_t encI[32768];       // 131072B [c][k][q]
  __shared__ __align__(16) uint32_t paL[4096];         // 16384B  P_a [q][l]
  __shared__ __align__(16) uint32_t pcL[1024];         // 4096B   P_c [q][j]
  __shared__ __align__(16) uint32_t owL[1024];         // 4096B   out_W [(c*16+a)*4+q]
  __shared__ __align__(16) uint32_t awpk[2][256];      // 2048B   raw exp pairs
  __shared__ __align__(16) uint32_t aplpk[2][64];      // 512B
  __shared__ __align__(16) uint32_t gip[G3_];          // 1536B   f16 pair (r0,r1)
  __shared__ __align__(16) uint32_t ghp[G3_];          // 1536B
  __shared__ __align__(16) uint32_t opk[2][64];        // 512B
  __shared__ __align__(16) uint32_t hpk[2][64];        // 512B
  __shared__ __align__(16) uint32_t inppk[2][8];       // 64B
  __shared__ float reds[2][8];                         // 64B

  const int tid = threadIdx.x, bid = blockIdx.x;
  const uint32_t* WBu  = (const uint32_t*)(ws + OFF_WB);
  const uint32_t* WIu  = (const uint32_t*)(ws + OFF_WIH);
  const uint32_t* WHu  = (const uint32_t*)(ws + OFF_WHH);
  const uint32_t* WCu  = (const uint32_t*)(ws + OFF_WC2);
  const uint32_t* PAu  = (const uint32_t*)(ws + OFF_PA);
  const uint32_t* PCu  = (const uint32_t*)(ws + OFF_PC);
  const uint32_t* OWu  = (const uint32_t*)(ws + OFF_OUTW);
  const float*    zb   = (const float*)(ws + OFF_ZB);
  const float*    obg  = (const float*)(ws + OFF_OB);
  const float*    hN   = (const float*)(ws + OFF_HN);

  // ---- register-stationary weights (round-6 proven) ----
  uint32_t wb[64], wA[64], wB[64];
  {
    const uint4* p = (const uint4*)(WBu + tid*64);
#pragma unroll
    for (int q = 0; q < 16; ++q) { uint4 v = p[q]; wb[q*4]=v.x; wb[q*4+1]=v.y; wb[q*4+2]=v.z; wb[q*4+3]=v.w; }
  }
  if (tid < G3_) {
    const uint4* p = (const uint4*)(WIu + tid*64);
    const uint4* p2 = (const uint4*)(WHu + tid*64);
#pragma unroll
    for (int q = 0; q < 16; ++q) {
      uint4 v = p[q];  wA[q*4]=v.x; wA[q*4+1]=v.y; wA[q*4+2]=v.z; wA[q*4+3]=v.w;
      uint4 w = p2[q]; wB[q*4]=w.x; wB[q*4+1]=w.y; wB[q*4+2]=w.z; wB[q*4+3]=w.w;
    }
  } else {
    const uint4* p = (const uint4*)(WCu + (tid-384)*64);
#pragma unroll
    for (int q = 0; q < 16; ++q) {
      uint4 v = p[q]; wA[q*4]=v.x; wA[q*4+1]=v.y; wA[q*4+2]=v.z; wA[q*4+3]=v.w;
    }
  }

  // ---- stage enc_outs into interleaved LDS layout ----
  {
    int k = tid & 127, ls = tid >> 7;
    const uint16_t* eg = (const uint16_t*)(ws + OFF_ENC);
    uint16_t* ei = (uint16_t*)encI;
    for (int cc = 0; cc < 16; ++cc) {
      int c = ls*16 + cc;
#pragma unroll
      for (int p = 0; p < 8; ++p) ei[(c*128 + k)*8 + p] = eg[(c*8 + p)*128 + k];
    }
  }
  // ---- stage P_a [q][l], P_c [q][j], out_W into LDS ----
  for (int idx = tid; idx < 4096; idx += 512) {
    int q = idx >> 9, l = idx & 511;
    paL[idx] = PAu[l*8 + q];
  }
  for (int idx = tid; idx < 1024; idx += 512) {
    int q = idx >> 7, j = idx & 127;
    pcL[idx] = PCu[j*8 + q];
    int qq = idx & 3, rest = idx >> 2, a = rest & 15, c = rest >> 4;
    owL[(c*16 + a)*4 + qq] = OWu[a*64 + c*4 + qq];
  }
  const float zbias    = zb[tid];
  const float bih_reg  = (tid < G3_) ? dec_bih[tid] : 0.f;
  const float bhh_reg  = (tid < G3_) ? dec_bhh[tid] : 0.f;
  const float ob_reg   = (tid >= G3_) ? obg[tid - G3_] : 0.f;
  const float outb_reg = (tid < 32) ? out_b[tid & 15] : 0.f;
  if (tid < 16) inppk[tid>>3][tid&7] = 0u;

  // persistent h in wave0: lane t holds h[r][2t], h[r][2t+1] for r=0,1
  float h00 = 0.f, h01 = 0.f, h10 = 0.f, h11 = 0.f;
  if (tid < 64) {
    h00 = hN[(2*bid + 0)*H_ + 2*tid];
    h01 = hN[(2*bid + 0)*H_ + 2*tid + 1];
    h10 = hN[(2*bid + 1)*H_ + 2*tid];
    h11 = hN[(2*bid + 1)*H_ + 2*tid + 1];
    hpk[0][tid] = pk2(h00, h01);
    hpk[1][tid] = pk2(h10, h11);
  }
  __syncthreads();

#pragma unroll 1
  for (int t = 0; t < L_; ++t) {
    // ---------- I1: attention logits, raw exp (max-free), wave sums ----------
    {
      uint32_t paq[8];
#pragma unroll
      for (int q = 0; q < 8; ++q) paq[q] = paL[q*512 + tid];
      uint4 i0 = LDS4(inppk[0], 0), i0b = LDS4(inppk[0], 4);
      uint4 i1 = LDS4(inppk[1], 0), i1b = LDS4(inppk[1], 4);
      float a0 = dot2f(paq[0], i0.x, zbias); a0 = dot2f(paq[1], i0.y, a0);
      a0 = dot2f(paq[2], i0.z, a0);          a0 = dot2f(paq[3], i0.w, a0);
      float b0 = dot2f(paq[4], i0b.x, 0.f);  b0 = dot2f(paq[5], i0b.y, b0);
      b0 = dot2f(paq[6], i0b.z, b0);         b0 = dot2f(paq[7], i0b.w, b0);
      float a1 = dot2f(paq[0], i1.x, zbias); a1 = dot2f(paq[1], i1.y, a1);
      a1 = dot2f(paq[2], i1.z, a1);          a1 = dot2f(paq[3], i1.w, a1);
      float b1 = dot2f(paq[4], i1b.x, 0.f);  b1 = dot2f(paq[5], i1b.y, b1);
      b1 = dot2f(paq[6], i1b.z, b1);         b1 = dot2f(paq[7], i1b.w, b1);
#pragma unroll
      for (int c = 0; c < 16; ++c) {
        uint4 h0 = LDS4(hpk[0], c*4); uint4 h1 = LDS4(hpk[1], c*4);
        a0 = dot2f(wb[c*4+0], h0.x, a0); a0 = dot2f(wb[c*4+1], h0.y, a0);
        b0 = dot2f(wb[c*4+2], h0.z, b0); b0 = dot2f(wb[c*4+3], h0.w, b0);
        a1 = dot2f(wb[c*4+0], h1.x, a1); a1 = dot2f(wb[c*4+1], h1.y, a1);
        b1 = dot2f(wb[c*4+2], h1.z, b1); b1 = dot2f(wb[c*4+3], h1.w, b1);
      }
      // max-free: |z| << 88 so raw expf is safe in f32
      float e0 = __expf(a0 + b0), e1 = __expf(a1 + b1);
      float s0 = e0, s1 = e1;
#pragma unroll
      for (int off = 32; off; off >>= 1) { s0 += __shfl_xor(s0, off); s1 += __shfl_xor(s1, off); }
      int wv = tid >> 6;
      if ((tid & 63) == 0) { reds[0][wv] = s0; reds[1][wv] = s1; }
      float ep0 = __shfl_xor(e0, 1), ep1 = __shfl_xor(e1, 1);
      if (!(tid & 1)) { awpk[0][tid>>1] = pk2(e0, ep0); awpk[1][tid>>1] = pk2(e1, ep1); }
    }
    __syncthreads();   // S1
    // ---------- I2: normalize + applied = aw @ enc_outs ----------
    {
      int k = tid >> 2, q4 = tid & 3;
      float S0 = 0.f, S1 = 0.f;
#pragma unroll
      for (int i = 0; i < 8; ++i) { S0 += reds[0][i]; S1 += reds[1][i]; }
      float is0 = 1.f / S0, is1 = 1.f / S1;
      float a00 = 0.f, a01 = 0.f, a10 = 0.f, a11 = 0.f;
#pragma unroll
      for (int cc = 0; cc < 16; ++cc) {
        int c = q4*16 + cc;
        uint4 ev = *(const uint4*)&encI[(c*128 + k)*4];
        uint4 w0 = LDS4(awpk[0], c*4);
        uint4 w1 = LDS4(awpk[1], c*4);
        a00 = dot2f(ev.x, w0.x, a00); a00 = dot2f(ev.y, w0.y, a00);
        a01 = dot2f(ev.z, w0.z, a01); a01 = dot2f(ev.w, w0.w, a01);
        a10 = dot2f(ev.x, w1.x, a10); a10 = dot2f(ev.y, w1.y, a10);
        a11 = dot2f(ev.z, w1.z, a11); a11 = dot2f(ev.w, w1.w, a11);
      }
      float v0 = (a00 + a01) * is0;
      float v1 = (a10 + a11) * is1;
      v0 += __shfl_xor(v0, 1); v0 += __shfl_xor(v0, 2);
      v1 += __shfl_xor(v1, 1); v1 += __shfl_xor(v1, 2);
      float p0 = __shfl_xor(v0, 4), p1x = __shfl_xor(v1, 4);
      if (!(tid & 7)) { aplpk[0][tid>>3] = pk2(v0, p0); aplpk[1][tid>>3] = pk2(v1, p1x); }
    }
    __syncthreads();   // S2
    // ---------- I3: {tid>=384: o = relu(...)} || {tid<384: gh} ----------
    if (tid >= G3_) {
      int jj = tid - G3_;
      uint32_t pcq[8];
#pragma unroll
      for (int q = 0; q < 8; ++q) pcq[q] = pcL[q*128 + jj];
      uint4 i0 = LDS4(inppk[0], 0), i0b = LDS4(inppk[0], 4);
      uint4 i1 = LDS4(inppk[1], 0), i1b = LDS4(inppk[1], 4);
      float o0 = dot2f(pcq[0], i0.x, ob_reg); o0 = dot2f(pcq[1], i0.y, o0);
      o0 = dot2f(pcq[2], i0.z, o0);           o0 = dot2f(pcq[3], i0.w, o0);
      float oa = dot2f(pcq[4], i0b.x, 0.f);   oa = dot2f(pcq[5], i0b.y, oa);
      oa = dot2f(pcq[6], i0b.z, oa);          oa = dot2f(pcq[7], i0b.w, oa);
      float o1 = dot2f(pcq[0], i1.x, ob_reg); o1 = dot2f(pcq[1], i1.y, o1);
      o1 = dot2f(pcq[2], i1.z, o1);           o1 = dot2f(pcq[3], i1.w, o1);
      float obb = dot2f(pcq[4], i1b.x, 0.f);  obb = dot2f(pcq[5], i1b.y, obb);
      obb = dot2f(pcq[6], i1b.z, obb);        obb = dot2f(pcq[7], i1b.w, obb);
#pragma unroll
      for (int c = 0; c < 16; ++c) {
        uint4 p0 = LDS4(aplpk[0], c*4); uint4 p1 = LDS4(aplpk[1], c*4);
        o0 = dot2f(wA[c*4+0], p0.x, o0); o0 = dot2f(wA[c*4+1], p0.y, o0);
        oa = dot2f(wA[c*4+2], p0.z, oa); oa = dot2f(wA[c*4+3], p0.w, oa);
        o1 = dot2f(wA[c*4+0], p1.x, o1); o1 = dot2f(wA[c*4+1], p1.y, o1);
        obb = dot2f(wA[c*4+2], p1.z, obb); obb = dot2f(wA[c*4+3], p1.w, obb);
      }
      o0 = fmaxf(o0 + oa, 0.f); o1 = fmaxf(o1 + obb, 0.f);
      float px0 = __shfl_xor(o0, 1), px1 = __shfl_xor(o1, 1);
      if (!(jj & 1)) { opk[0][jj>>1] = pk2(o0, px0); opk[1][jj>>1] = pk2(o1, px1); }
    } else {
      float e0g = bhh_reg, e1g = e0g, ea = 0.f, eb = 0.f;
#pragma unroll
      for (int c = 0; c < 16; ++c) {
        uint4 h0 = LDS4(hpk[0], c*4); uint4 h1 = LDS4(hpk[1], c*4);
        e0g = dot2f(wB[c*4+0], h0.x, e0g); e0g = dot2f(wB[c*4+1], h0.y, e0g);
        ea  = dot2f(wB[c*4+2], h0.z, ea);  ea  = dot2f(wB[c*4+3], h0.w, ea);
        e1g = dot2f(wB[c*4+0], h1.x, e1g); e1g = dot2f(wB[c*4+1], h1.y, e1g);
        eb  = dot2f(wB[c*4+2], h1.z, eb);  eb  = dot2f(wB[c*4+3], h1.w, eb);
      }
      ghp[tid] = pk2(e0g + ea, e1g + eb);
    }
    __syncthreads();   // S3
    // ---------- I4: gi = o@Wih^T + bih ----------
    if (tid < G3_) {
      float g0 = bih_reg, g1 = g0, ga = 0.f, gb = 0.f;
#pragma unroll
      for (int c = 0; c < 16; ++c) {
        uint4 o0 = LDS4(opk[0], c*4); uint4 o1 = LDS4(opk[1], c*4);
        g0 = dot2f(wA[c*4+0], o0.x, g0); g0 = dot2f(wA[c*4+1], o0.y, g0);
        ga = dot2f(wA[c*4+2], o0.z, ga); ga = dot2f(wA[c*4+3], o0.w, ga);
        g1 = dot2f(wA[c*4+0], o1.x, g1); g1 = dot2f(wA[c*4+1], o1.y, g1);
        gb = dot2f(wA[c*4+2], o1.z, gb); gb = dot2f(wA[c*4+3], o1.w, gb);
      }
      gip[tid] = pk2(g0 + ga, g1 + gb);
    }
    __syncthreads();   // S4
    // ---------- I5 (fused, wave0): gates -> y=h@outW -> log_softmax -> feedback ----------
    if (tid < 64) {
      // packed (row0,row1) gi/gh for dims 2t, 2t+1
      uint2 gA = *(const uint2*)&gip[2*tid];
      uint2 gB = *(const uint2*)&gip[128 + 2*tid];
      uint2 gC = *(const uint2*)&gip[256 + 2*tid];
      uint2 eA = *(const uint2*)&ghp[2*tid];
      uint2 eB = *(const uint2*)&ghp[128 + 2*tid];
      uint2 eC = *(const uint2*)&ghp[256 + 2*tid];
#define PX(u) ((float)(__builtin_bit_cast(f16x2_t,(u)).x))
#define PY(u) ((float)(__builtin_bit_cast(f16x2_t,(u)).y))
      h00 = gru1(PX(gA.x), PX(gB.x), PX(gC.x), PX(eA.x), PX(eB.x), PX(eC.x), h00);
      h01 = gru1(PX(gA.y), PX(gB.y), PX(gC.y), PX(eA.y), PX(eB.y), PX(eC.y), h01);
      h10 = gru1(PY(gA.x), PY(gB.x), PY(gC.x), PY(eA.x), PY(eB.x), PY(eC.x), h10);
      h11 = gru1(PY(gA.y), PY(gB.y), PY(gC.y), PY(eA.y), PY(eB.y), PY(eC.y), h11);
#undef PX
#undef PY
      hpk[0][tid] = pk2(h00, h01);
      hpk[1][tid] = pk2(h10, h11);
      // in-wave LDS write->read ordering (wave0 only; pattern verified r8)
      asm volatile("s_waitcnt lgkmcnt(0)" ::: "memory");
      int a = tid & 15, grp = tid >> 4;       // grp: bit0 = row, bit1 = k-half
      int rr = grp & 1, kh = grp >> 1;
      float y = kh ? 0.f : outb_reg;
#pragma unroll
      for (int cc = 0; cc < 8; ++cc) {
        int c = kh*8 + cc;
        uint4 ww = *(const uint4*)&owL[(c*16 + a)*4];
        uint4 hb = LDS4(hpk[rr], c*4);
        y = dot2f(ww.x, hb.x, y); y = dot2f(ww.y, hb.y, y);
        y = dot2f(ww.z, hb.z, y); y = dot2f(ww.w, hb.w, y);
      }
      y += __shfl_xor(y, 32);                 // combine k-halves
      if (tid < 32) {                         // lanes: rr=0 -> 0..15, rr=1 -> 16..31
        float e = __expf(y);                  // |y| small: max-free safe
        float s = e;
#pragma unroll
        for (int off = 8; off; off >>= 1) s += __shfl_xor(s, off);
        float lsf = y - __logf(s);
        if (t == L_-1) dout[(2*bid + rr)*A_ + a] = lsf;
        float pr = __shfl_xor(lsf, 1);
        if (!(a & 1)) inppk[rr][a >> 1] = pk2(lsf, pr);
      }
    }
    __syncthreads();   // S5
  }
}

// =====================================================================
extern "C" void kernel_launch(void* const* d_in, const int* in_sizes, int n_in,
                              void* d_out, int out_size, void* d_ws, size_t ws_size,
                              hipStream_t stream) {
  (void)in_sizes; (void)n_in; (void)out_size; (void)ws_size;
  const float* obs       = (const float*)d_in[0];
  const float* enc_emb_W = (const float*)d_in[1];
  const float* enc_emb_b = (const float*)d_in[2];
  const float* enc_Wih   = (const float*)d_in[3];
  const float* enc_Whh   = (const float*)d_in[4];
  const float* enc_bih   = (const float*)d_in[5];
  const float* enc_bhh   = (const float*)d_in[6];
  const float* dec_emb_W = (const float*)d_in[7];
  const float* dec_emb_b = (const float*)d_in[8];
  const float* attn_W    = (const float*)d_in[9];
  const float* attn_b    = (const float*)d_in[10];
  const float* comb_W    = (const float*)d_in[11];
  const float* comb_b    = (const float*)d_in[12];
  const float* dec_Wih   = (const float*)d_in[13];
  const float* dec_Whh   = (const float*)d_in[14];
  const float* dec_bih   = (const float*)d_in[15];
  const float* dec_bhh   = (const float*)d_in[16];
  const float* out_W     = (const float*)d_in[17];
  const float* out_b     = (const float*)d_in[18];
  char* ws = (char*)d_ws;

  hipLaunchKernelGGL(prep_kernel, dim3(1140), dim3(256), 0, stream,
                     enc_emb_W, enc_emb_b, enc_Wih, enc_bih, dec_emb_W, dec_emb_b,
                     attn_W, attn_b, comb_W, comb_b, dec_Wih, dec_Whh, enc_Whh, out_W, ws);
  hipLaunchKernelGGL(enc_kernel, dim3(256), dim3(512), 0, stream, obs, enc_bhh, ws);
  hipLaunchKernelGGL(dec_kernel, dim3(256), dim3(512), 0, stream,
                     dec_bih, dec_bhh, out_b, ws, (float*)d_out);
}

// Round 10
// 4108.276 us; speedup vs baseline: 3.9726x; 1.3231x over previous
//
#include <hip/hip_runtime.h>
#include <stdint.h>

#define H_  128
#define L_  512
#define B_  512
#define A_  16
#define G3_ 384

// ---------------- workspace layout (bytes) ----------------
#define OFF_M1    0          // f16 [384][128]  enc: Wih@enc_emb_W
#define OFF_WHHE  98304      // f16 [384][128]  enc_Whh
#define OFF_WB    196608     // f16 [512][128]  attn_W[:,128:]
#define OFF_WIH   327680     // f16 [384][128]  dec_Wih
#define OFF_WHH   425984     // f16 [384][128]  dec_Whh
#define OFF_WC2   524288     // f16 [128][128]  comb_W[:,128:]
#define OFF_PA    557056     // f16 [512][16]   Wa@dec_emb_W
#define OFF_PC    573440     // f16 [128][16]   Wc1@dec_emb_W
#define OFF_OUTW  577536     // f16 [16][128]
#define OFF_BGI   581632     // f32 [384]  bih + Wih@enc_emb_b
#define OFF_ZB    583168     // f32 [512]  attn_b + Wa@dec_emb_b
#define OFF_OB    585216     // f32 [128]  comb_b + Wc1@dec_emb_b
#define OFF_ENC   585728     // f16 [512][128]  enc_outs
#define OFF_HN    716800     // f32 [512][128]  final encoder hidden

typedef _Float16 f16_t;
typedef __attribute__((ext_vector_type(2))) _Float16 f16x2_t;

__device__ __forceinline__ float dot2f(uint32_t w, uint32_t a, float acc) {
#if __has_builtin(__builtin_amdgcn_fdot2)
  return __builtin_amdgcn_fdot2(__builtin_bit_cast(f16x2_t, w),
                                __builtin_bit_cast(f16x2_t, a), acc, false);
#else
  f16x2_t x = __builtin_bit_cast(f16x2_t, w);
  f16x2_t y = __builtin_bit_cast(f16x2_t, a);
  return acc + (float)x.x * (float)y.x + (float)x.y * (float)y.y;
#endif
}

__device__ __forceinline__ uint32_t pk2(float lo, float hi) {
#if __has_builtin(__builtin_amdgcn_cvt_pkrtz)
  return __builtin_bit_cast(uint32_t, __builtin_amdgcn_cvt_pkrtz(lo, hi));
#else
  f16x2_t v; v.x = (_Float16)lo; v.y = (_Float16)hi;
  return __builtin_bit_cast(uint32_t, v);
#endif
}

__device__ __forceinline__ float sigm(float x) { return 1.f / (1.f + __expf(-x)); }
__device__ __forceinline__ float tanh_s(float t) { float ex = __expf(2.f * t); return 1.f - 2.f / (ex + 1.f); }
__device__ __forceinline__ float gru1(float ir, float iz, float in_, float hr, float hz, float hn, float h) {
  float rg = sigm(ir + hr);
  float zg = sigm(iz + hz);
  float nn = tanh_s(in_ + rg * hn);
  return (1.f - zg) * nn + zg * h;
}

#define LDS4(arr, idx) (*(const uint4*)&(arr)[(idx)])

// =====================================================================
// prep: weight folds + f16 conversions (unchanged)
// =====================================================================
__global__ void prep_kernel(const float* __restrict__ enc_emb_W, const float* __restrict__ enc_emb_b,
                            const float* __restrict__ enc_Wih, const float* __restrict__ enc_bih,
                            const float* __restrict__ dec_emb_W, const float* __restrict__ dec_emb_b,
                            const float* __restrict__ attn_W, const float* __restrict__ attn_b,
                            const float* __restrict__ comb_W, const float* __restrict__ comb_b,
                            const float* __restrict__ dec_Wih, const float* __restrict__ dec_Whh,
                            const float* __restrict__ enc_Whh, const float* __restrict__ out_W,
                            char* __restrict__ ws) {
  int t = blockIdx.x * 256 + threadIdx.x;
  if (t < 49152) {                       // M1 [384][128]
    int n = t >> 7, d = t & 127; float acc = 0.f;
    for (int h = 0; h < 128; ++h) acc += enc_Wih[n*128+h] * enc_emb_W[h*128+d];
    ((f16_t*)(ws+OFF_M1))[t] = (f16_t)acc; return;
  } t -= 49152;
  if (t < 384) {                         // bias_gi
    float acc = enc_bih[t];
    for (int h = 0; h < 128; ++h) acc += enc_Wih[t*128+h] * enc_emb_b[h];
    ((float*)(ws+OFF_BGI))[t] = acc; return;
  } t -= 384;
  if (t < 8192) {                        // P_a [512][16]
    int l = t >> 4, a = t & 15; float acc = 0.f;
    for (int k = 0; k < 128; ++k) acc += attn_W[l*256+k] * dec_emb_W[k*16+a];
    ((f16_t*)(ws+OFF_PA))[t] = (f16_t)acc; return;
  } t -= 8192;
  if (t < 512) {                         // zbias [512]
    float acc = attn_b[t];
    for (int k = 0; k < 128; ++k) acc += attn_W[t*256+k] * dec_emb_b[k];
    ((float*)(ws+OFF_ZB))[t] = acc; return;
  } t -= 512;
  if (t < 2048) {                        // P_c [128][16]
    int j = t >> 4, a = t & 15; float acc = 0.f;
    for (int k = 0; k < 128; ++k) acc += comb_W[j*256+k] * dec_emb_W[k*16+a];
    ((f16_t*)(ws+OFF_PC))[t] = (f16_t)acc; return;
  } t -= 2048;
  if (t < 128) {                         // obias [128]
    float acc = comb_b[t];
    for (int k = 0; k < 128; ++k) acc += comb_W[t*256+k] * dec_emb_b[k];
    ((float*)(ws+OFF_OB))[t] = acc; return;
  } t -= 128;
  if (t < 65536) {                       // Wb [512][128]
    int l = t >> 7, k = t & 127;
    ((f16_t*)(ws+OFF_WB))[t] = (f16_t)attn_W[l*256+128+k]; return;
  } t -= 65536;
  if (t < 49152) { ((f16_t*)(ws+OFF_WHHE))[t] = (f16_t)enc_Whh[t]; return; } t -= 49152;
  if (t < 49152) { ((f16_t*)(ws+OFF_WIH))[t]  = (f16_t)dec_Wih[t]; return; } t -= 49152;
  if (t < 49152) { ((f16_t*)(ws+OFF_WHH))[t]  = (f16_t)dec_Whh[t]; return; } t -= 49152;
  if (t < 16384) {                       // Wc2 [128][128]
    int j = t >> 7, k = t & 127;
    ((f16_t*)(ws+OFF_WC2))[t] = (f16_t)comb_W[j*256+128+k]; return;
  } t -= 16384;
  if (t < 2048) { ((f16_t*)(ws+OFF_OUTW))[t] = (f16_t)out_W[t]; return; }
}

// =====================================================================
// encoder: 256 blocks x 512 thr, rows (2b, 2b+1), 512 steps
// (round-6 proven config)
// =====================================================================
__global__ __launch_bounds__(512, 1) void enc_kernel(const float* __restrict__ obs,
                                                     const float* __restrict__ enc_bhh,
                                                     char* __restrict__ ws) {
  __shared__ __align__(16) uint32_t obspk[2][64];
  __shared__ __align__(16) uint32_t hpk[2][64];
  __shared__ __align__(16) float    gi_s[2][G3_];
  __shared__ __align__(16) float    gh_s[2][G3_];
  __shared__ float bgi_s[G3_], bhh_s[G3_];

  const int tid = threadIdx.x, bid = blockIdx.x;
  const uint32_t* M1u  = (const uint32_t*)(ws + OFF_M1);
  const uint32_t* WHu  = (const uint32_t*)(ws + OFF_WHHE);
  const float*    bgi  = (const float*)(ws + OFF_BGI);
  f16_t* encw = (f16_t*)(ws + OFF_ENC);
  float* hN   = (float*)(ws + OFF_HN);

  uint32_t m1r[64], whr[64];
  if (tid < G3_) {
    const uint4* p1 = (const uint4*)(M1u + tid*64);
    const uint4* p2 = (const uint4*)(WHu + tid*64);
#pragma unroll
    for (int q = 0; q < 16; ++q) {
      uint4 v = p1[q]; m1r[q*4]=v.x; m1r[q*4+1]=v.y; m1r[q*4+2]=v.z; m1r[q*4+3]=v.w;
      uint4 w = p2[q]; whr[q*4]=w.x; whr[q*4+1]=w.y; whr[q*4+2]=w.z; whr[q*4+3]=w.w;
    }
    bgi_s[tid] = bgi[tid]; bhh_s[tid] = enc_bhh[tid];
  }

  const int r = tid >> 7, jj = tid & 127;   // valid for tid<256
  const size_t rowbase = (size_t)(2*bid + r) * L_ * H_ + jj;
  float hreg = 0.f;
  float oA = 0.f;
  if (tid < 256) {
    float o0 = obs[rowbase + 0*H_];
    float op = __shfl_xor(o0, 1);
    if (!(jj & 1)) obspk[r][jj >> 1] = pk2(o0, op);
    oA = obs[rowbase + 1*H_];
  }
  if (tid < 128) hpk[tid>>6][tid&63] = 0u;
  __syncthreads();

#pragma unroll 1
  for (int t = 0; t < L_; ++t) {
    float oB = 0.f;
    if (tid < 256) {
      int tn = (t+2 < L_) ? t+2 : L_-1;
      oB = obs[rowbase + (size_t)tn*H_];
    }
    if (tid < G3_) {
      float g0 = bgi_s[tid], g1 = g0, ga = 0.f, gb = 0.f;
      float e0 = bhh_s[tid], e1 = e0, ea = 0.f, eb = 0.f;
#pragma unroll
      for (int c = 0; c < 16; ++c) {
        uint4 o0 = LDS4(obspk[0], c*4); uint4 o1 = LDS4(obspk[1], c*4);
        uint4 h0 = LDS4(hpk[0],  c*4);  uint4 h1 = LDS4(hpk[1],  c*4);
        g0 = dot2f(m1r[c*4+0], o0.x, g0); g0 = dot2f(m1r[c*4+1], o0.y, g0);
        ga = dot2f(m1r[c*4+2], o0.z, ga); ga = dot2f(m1r[c*4+3], o0.w, ga);
        g1 = dot2f(m1r[c*4+0], o1.x, g1); g1 = dot2f(m1r[c*4+1], o1.y, g1);
        gb = dot2f(m1r[c*4+2], o1.z, gb); gb = dot2f(m1r[c*4+3], o1.w, gb);
        e0 = dot2f(whr[c*4+0], h0.x, e0); e0 = dot2f(whr[c*4+1], h0.y, e0);
        ea = dot2f(whr[c*4+2], h0.z, ea); ea = dot2f(whr[c*4+3], h0.w, ea);
        e1 = dot2f(whr[c*4+0], h1.x, e1); e1 = dot2f(whr[c*4+1], h1.y, e1);
        eb = dot2f(whr[c*4+2], h1.z, eb); eb = dot2f(whr[c*4+3], h1.w, eb);
      }
      gi_s[0][tid] = g0+ga; gi_s[1][tid] = g1+gb;
      gh_s[0][tid] = e0+ea; gh_s[1][tid] = e1+eb;
    }
    __syncthreads();
    if (tid < 256) {
      float ir = gi_s[r][jj], iz = gi_s[r][jj+128], in_ = gi_s[r][jj+256];
      float hr = gh_s[r][jj], hz = gh_s[r][jj+128], hn = gh_s[r][jj+256];
      float h2 = gru1(ir, iz, in_, hr, hz, hn, hreg);
      hreg = h2;
      float hp = __shfl_xor(h2, 1);
      float op = __shfl_xor(oA, 1);
      if (!(jj & 1)) {
        hpk[r][jj >> 1] = pk2(h2, hp);
        obspk[r][jj >> 1] = pk2(oA, op);
      }
      if (bid == 0 && r == 0) encw[t*H_ + jj] = (f16_t)h2;
      oA = oB;
    }
    __syncthreads();
  }
  if (tid < 256) hN[(2*bid + r)*H_ + jj] = hreg;
}

// =====================================================================
// decoder: 256 blocks x 512 thr, rows (2b, 2b+1), 512 steps.
// Round-6 proven base (encI in LDS, (512,1), weights in regs/AGPR,
// padded awpk + round-6 I2 wave-mapping: 4.2M bank-conflict cycles),
// + max-free softmax, + fused gates/output/log-softmax wave0 phase.
// 5 barriers/step; zero in-loop global traffic.
// =====================================================================
__global__ __launch_bounds__(512, 1) void dec_kernel(const float* __restrict__ dec_bih,
                                                     const float* __restrict__ dec_bhh,
                                                     const float* __restrict__ out_b,
                                                     char* __restrict__ ws,
                                                     float* __restrict__ dout) {
  __shared__ __align__(16) uint32_t encI[32768];       // 131072B [c][k][q]
  __shared__ __align__(16) uint32_t paL[4096];         // 16384B  P_a [q][l]
  __shared__ __align__(16) uint32_t pcL[1024];         // 4096B   P_c [q][j]
  __shared__ __align__(16) uint32_t owL[1024];         // 4096B   out_W [(c*16+a)*4+q]
  __shared__ __align__(16) uint32_t awpk[2][272];      // 2176B   raw exp pairs, +4w pad/64
  __shared__ __align__(16) uint32_t aplpk[2][64];      // 512B
  __shared__ __align__(16) uint32_t gip[G3_];          // 1536B   f16 pair (r0,r1)
  __shared__ __align__(16) uint32_t ghp[G3_];          // 1536B
  __shared__ __align__(16) uint32_t opk[2][64];        // 512B
  __shared__ __align__(16) uint32_t hpk[2][64];        // 512B
  __shared__ __align__(16) uint32_t inppk[2][8];       // 64B
  __shared__ float reds[2][8];                         // 64B

  const int tid = threadIdx.x, bid = blockIdx.x;
  const uint32_t* WBu  = (const uint32_t*)(ws + OFF_WB);
  const uint32_t* WIu  = (const uint32_t*)(ws + OFF_WIH);
  const uint32_t* WHu  = (const uint32_t*)(ws + OFF_WHH);
  const uint32_t* WCu  = (const uint32_t*)(ws + OFF_WC2);
  const uint32_t* PAu  = (const uint32_t*)(ws + OFF_PA);
  const uint32_t* PCu  = (const uint32_t*)(ws + OFF_PC);
  const uint32_t* OWu  = (const uint32_t*)(ws + OFF_OUTW);
  const float*    zb   = (const float*)(ws + OFF_ZB);
  const float*    obg  = (const float*)(ws + OFF_OB);
  const float*    hN   = (const float*)(ws + OFF_HN);

  // ---- register-stationary weights (round-6 proven) ----
  uint32_t wb[64], wA[64], wB[64];
  {
    const uint4* p = (const uint4*)(WBu + tid*64);
#pragma unroll
    for (int q = 0; q < 16; ++q) { uint4 v = p[q]; wb[q*4]=v.x; wb[q*4+1]=v.y; wb[q*4+2]=v.z; wb[q*4+3]=v.w; }
  }
  if (tid < G3_) {
    const uint4* p = (const uint4*)(WIu + tid*64);
    const uint4* p2 = (const uint4*)(WHu + tid*64);
#pragma unroll
    for (int q = 0; q < 16; ++q) {
      uint4 v = p[q];  wA[q*4]=v.x; wA[q*4+1]=v.y; wA[q*4+2]=v.z; wA[q*4+3]=v.w;
      uint4 w = p2[q]; wB[q*4]=w.x; wB[q*4+1]=w.y; wB[q*4+2]=w.z; wB[q*4+3]=w.w;
    }
  } else {
    const uint4* p = (const uint4*)(WCu + (tid-384)*64);
#pragma unroll
    for (int q = 0; q < 16; ++q) {
      uint4 v = p[q]; wA[q*4]=v.x; wA[q*4+1]=v.y; wA[q*4+2]=v.z; wA[q*4+3]=v.w;
    }
  }

  // ---- stage enc_outs into interleaved LDS layout ----
  {
    int k = tid & 127, ls = tid >> 7;
    const uint16_t* eg = (const uint16_t*)(ws + OFF_ENC);
    uint16_t* ei = (uint16_t*)encI;
    for (int cc = 0; cc < 16; ++cc) {
      int c = ls*16 + cc;
#pragma unroll
      for (int p = 0; p < 8; ++p) ei[(c*128 + k)*8 + p] = eg[(c*8 + p)*128 + k];
    }
  }
  // ---- stage P_a [q][l], P_c [q][j], out_W into LDS ----
  for (int idx = tid; idx < 4096; idx += 512) {
    int q = idx >> 9, l = idx & 511;
    paL[idx] = PAu[l*8 + q];
  }
  for (int idx = tid; idx < 1024; idx += 512) {
    int q = idx >> 7, j = idx & 127;
    pcL[idx] = PCu[j*8 + q];
    int qq = idx & 3, rest = idx >> 2, a = rest & 15, c = rest >> 4;
    owL[(c*16 + a)*4 + qq] = OWu[a*64 + c*4 + qq];
  }
  const float zbias    = zb[tid];
  const float bih_reg  = (tid < G3_) ? dec_bih[tid] : 0.f;
  const float bhh_reg  = (tid < G3_) ? dec_bhh[tid] : 0.f;
  const float ob_reg   = (tid >= G3_) ? obg[tid - G3_] : 0.f;
  const float outb_reg = (tid < 32) ? out_b[tid & 15] : 0.f;
  if (tid < 16) inppk[tid>>3][tid&7] = 0u;

  // persistent h in wave0: lane t holds h[r][2t], h[r][2t+1] for r=0,1
  float h00 = 0.f, h01 = 0.f, h10 = 0.f, h11 = 0.f;
  if (tid < 64) {
    h00 = hN[(2*bid + 0)*H_ + 2*tid];
    h01 = hN[(2*bid + 0)*H_ + 2*tid + 1];
    h10 = hN[(2*bid + 1)*H_ + 2*tid];
    h11 = hN[(2*bid + 1)*H_ + 2*tid + 1];
    hpk[0][tid] = pk2(h00, h01);
    hpk[1][tid] = pk2(h10, h11);
  }
  __syncthreads();

#pragma unroll 1
  for (int t = 0; t < L_; ++t) {
    // ---------- I1: attention logits, raw exp (max-free), wave sums ----------
    {
      uint32_t paq[8];
#pragma unroll
      for (int q = 0; q < 8; ++q) paq[q] = paL[q*512 + tid];
      uint4 i0 = LDS4(inppk[0], 0), i0b = LDS4(inppk[0], 4);
      uint4 i1 = LDS4(inppk[1], 0), i1b = LDS4(inppk[1], 4);
      float a0 = dot2f(paq[0], i0.x, zbias); a0 = dot2f(paq[1], i0.y, a0);
      a0 = dot2f(paq[2], i0.z, a0);          a0 = dot2f(paq[3], i0.w, a0);
      float b0 = dot2f(paq[4], i0b.x, 0.f);  b0 = dot2f(paq[5], i0b.y, b0);
      b0 = dot2f(paq[6], i0b.z, b0);         b0 = dot2f(paq[7], i0b.w, b0);
      float a1 = dot2f(paq[0], i1.x, zbias); a1 = dot2f(paq[1], i1.y, a1);
      a1 = dot2f(paq[2], i1.z, a1);          a1 = dot2f(paq[3], i1.w, a1);
      float b1 = dot2f(paq[4], i1b.x, 0.f);  b1 = dot2f(paq[5], i1b.y, b1);
      b1 = dot2f(paq[6], i1b.z, b1);         b1 = dot2f(paq[7], i1b.w, b1);
#pragma unroll
      for (int c = 0; c < 16; ++c) {
        uint4 h0 = LDS4(hpk[0], c*4); uint4 h1 = LDS4(hpk[1], c*4);
        a0 = dot2f(wb[c*4+0], h0.x, a0); a0 = dot2f(wb[c*4+1], h0.y, a0);
        b0 = dot2f(wb[c*4+2], h0.z, b0); b0 = dot2f(wb[c*4+3], h0.w, b0);
        a1 = dot2f(wb[c*4+0], h1.x, a1); a1 = dot2f(wb[c*4+1], h1.y, a1);
        b1 = dot2f(wb[c*4+2], h1.z, b1); b1 = dot2f(wb[c*4+3], h1.w, b1);
      }
      // max-free: |z| << 88 so raw expf is safe in f32
      float e0 = __expf(a0 + b0), e1 = __expf(a1 + b1);
      float s0 = e0, s1 = e1;
#pragma unroll
      for (int off = 32; off; off >>= 1) { s0 += __shfl_xor(s0, off); s1 += __shfl_xor(s1, off); }
      int wv = tid >> 6;
      if ((tid & 63) == 0) { reds[0][wv] = s0; reds[1][wv] = s1; }
      float ep0 = __shfl_xor(e0, 1), ep1 = __shfl_xor(e1, 1);
      int awi = (tid >> 1) + ((tid >> 7) << 2);   // +4-word pad per 64 pairs
      if (!(tid & 1)) { awpk[0][awi] = pk2(e0, ep0); awpk[1][awi] = pk2(e1, ep1); }
    }
    __syncthreads();   // S1
    // ---------- I2: normalize + applied = aw @ enc_outs (round-6 mapping) ----------
    {
      int lane = tid & 63, wv3 = tid >> 6;
      int k = wv3*16 + (lane & 15), chunk = lane >> 4;
      float S0 = 0.f, S1 = 0.f;
#pragma unroll
      for (int i = 0; i < 8; ++i) { S0 += reds[0][i]; S1 += reds[1][i]; }
      float is0 = 1.f / S0, is1 = 1.f / S1;
      int eb0 = chunk*8192 + k*4;
      int awb = chunk*68;
      float a00=0.f, a01=0.f, a10=0.f, a11=0.f;
#pragma unroll
      for (int cc = 0; cc < 8; ++cc) {
        uint4 ev = *(const uint4*)&encI[eb0 + cc*512];
        uint4 w0 = *(const uint4*)&awpk[0][awb + cc*4];
        uint4 wq = *(const uint4*)&awpk[1][awb + cc*4];
        a00 = dot2f(ev.x, w0.x, a00); a00 = dot2f(ev.y, w0.y, a00);
        a00 = dot2f(ev.z, w0.z, a00); a00 = dot2f(ev.w, w0.w, a00);
        a10 = dot2f(ev.x, wq.x, a10); a10 = dot2f(ev.y, wq.y, a10);
        a10 = dot2f(ev.z, wq.z, a10); a10 = dot2f(ev.w, wq.w, a10);
      }
#pragma unroll
      for (int cc = 8; cc < 16; ++cc) {
        uint4 ev = *(const uint4*)&encI[eb0 + cc*512];
        uint4 w0 = *(const uint4*)&awpk[0][awb + cc*4];
        uint4 wq = *(const uint4*)&awpk[1][awb + cc*4];
        a01 = dot2f(ev.x, w0.x, a01); a01 = dot2f(ev.y, w0.y, a01);
        a01 = dot2f(ev.z, w0.z, a01); a01 = dot2f(ev.w, w0.w, a01);
        a11 = dot2f(ev.x, wq.x, a11); a11 = dot2f(ev.y, wq.y, a11);
        a11 = dot2f(ev.z, wq.z, a11); a11 = dot2f(ev.w, wq.w, a11);
      }
      float v0 = (a00 + a01) * is0;
      float v1 = (a10 + a11) * is1;
      v0 += __shfl_xor(v0, 16); v0 += __shfl_xor(v0, 32);
      v1 += __shfl_xor(v1, 16); v1 += __shfl_xor(v1, 32);
      float v0p = __shfl_xor(v0, 1), v1p = __shfl_xor(v1, 1);
      if (!(lane & 49)) {
        int kk = k >> 1;
        aplpk[0][kk] = pk2(v0, v0p); aplpk[1][kk] = pk2(v1, v1p);
      }
    }
    __syncthreads();   // S2
    // ---------- I3: {tid>=384: o = relu(...)} || {tid<384: gh} ----------
    if (tid >= G3_) {
      int jj = tid - G3_;
      uint32_t pcq[8];
#pragma unroll
      for (int q = 0; q < 8; ++q) pcq[q] = pcL[q*128 + jj];
      uint4 i0 = LDS4(inppk[0], 0), i0b = LDS4(inppk[0], 4);
      uint4 i1 = LDS4(inppk[1], 0), i1b = LDS4(inppk[1], 4);
      float o0 = dot2f(pcq[0], i0.x, ob_reg); o0 = dot2f(pcq[1], i0.y, o0);
      o0 = dot2f(pcq[2], i0.z, o0);           o0 = dot2f(pcq[3], i0.w, o0);
      float oa = dot2f(pcq[4], i0b.x, 0.f);   oa = dot2f(pcq[5], i0b.y, oa);
      oa = dot2f(pcq[6], i0b.z, oa);          oa = dot2f(pcq[7], i0b.w, oa);
      float o1 = dot2f(pcq[0], i1.x, ob_reg); o1 = dot2f(pcq[1], i1.y, o1);
      o1 = dot2f(pcq[2], i1.z, o1);           o1 = dot2f(pcq[3], i1.w, o1);
      float obb = dot2f(pcq[4], i1b.x, 0.f);  obb = dot2f(pcq[5], i1b.y, obb);
      obb = dot2f(pcq[6], i1b.z, obb);        obb = dot2f(pcq[7], i1b.w, obb);
#pragma unroll
      for (int c = 0; c < 16; ++c) {
        uint4 p0 = LDS4(aplpk[0], c*4); uint4 p1 = LDS4(aplpk[1], c*4);
        o0 = dot2f(wA[c*4+0], p0.x, o0); o0 = dot2f(wA[c*4+1], p0.y, o0);
        oa = dot2f(wA[c*4+2], p0.z, oa); oa = dot2f(wA[c*4+3], p0.w, oa);
        o1 = dot2f(wA[c*4+0], p1.x, o1); o1 = dot2f(wA[c*4+1], p1.y, o1);
        obb = dot2f(wA[c*4+2], p1.z, obb); obb = dot2f(wA[c*4+3], p1.w, obb);
      }
      o0 = fmaxf(o0 + oa, 0.f); o1 = fmaxf(o1 + obb, 0.f);
      float px0 = __shfl_xor(o0, 1), px1 = __shfl_xor(o1, 1);
      if (!(jj & 1)) { opk[0][jj>>1] = pk2(o0, px0); opk[1][jj>>1] = pk2(o1, px1); }
    } else {
      float e0g = bhh_reg, e1g = e0g, ea = 0.f, eb = 0.f;
#pragma unroll
      for (int c = 0; c < 16; ++c) {
        uint4 h0 = LDS4(hpk[0], c*4); uint4 h1 = LDS4(hpk[1], c*4);
        e0g = dot2f(wB[c*4+0], h0.x, e0g); e0g = dot2f(wB[c*4+1], h0.y, e0g);
        ea  = dot2f(wB[c*4+2], h0.z, ea);  ea  = dot2f(wB[c*4+3], h0.w, ea);
        e1g = dot2f(wB[c*4+0], h1.x, e1g); e1g = dot2f(wB[c*4+1], h1.y, e1g);
        eb  = dot2f(wB[c*4+2], h1.z, eb);  eb  = dot2f(wB[c*4+3], h1.w, eb);
      }
      ghp[tid] = pk2(e0g + ea, e1g + eb);
    }
    __syncthreads();   // S3
    // ---------- I4: gi = o@Wih^T + bih ----------
    if (tid < G3_) {
      float g0 = bih_reg, g1 = g0, ga = 0.f, gb = 0.f;
#pragma unroll
      for (int c = 0; c < 16; ++c) {
        uint4 o0 = LDS4(opk[0], c*4); uint4 o1 = LDS4(opk[1], c*4);
        g0 = dot2f(wA[c*4+0], o0.x, g0); g0 = dot2f(wA[c*4+1], o0.y, g0);
        ga = dot2f(wA[c*4+2], o0.z, ga); ga = dot2f(wA[c*4+3], o0.w, ga);
        g1 = dot2f(wA[c*4+0], o1.x, g1); g1 = dot2f(wA[c*4+1], o1.y, g1);
        gb = dot2f(wA[c*4+2], o1.z, gb); gb = dot2f(wA[c*4+3], o1.w, gb);
      }
      gip[tid] = pk2(g0 + ga, g1 + gb);
    }
    __syncthreads();   // S4
    // ---------- I5 (fused, wave0): gates -> y=h@outW -> log_softmax -> feedback ----------
    if (tid < 64) {
      // packed (row0,row1) gi/gh for dims 2t, 2t+1
      uint2 gA = *(const uint2*)&gip[2*tid];
      uint2 gB = *(const uint2*)&gip[128 + 2*tid];
      uint2 gC = *(const uint2*)&gip[256 + 2*tid];
      uint2 eA = *(const uint2*)&ghp[2*tid];
      uint2 eB = *(const uint2*)&ghp[128 + 2*tid];
      uint2 eC = *(const uint2*)&ghp[256 + 2*tid];
#define PX(u) ((float)(__builtin_bit_cast(f16x2_t,(u)).x))
#define PY(u) ((float)(__builtin_bit_cast(f16x2_t,(u)).y))
      h00 = gru1(PX(gA.x), PX(gB.x), PX(gC.x), PX(eA.x), PX(eB.x), PX(eC.x), h00);
      h01 = gru1(PX(gA.y), PX(gB.y), PX(gC.y), PX(eA.y), PX(eB.y), PX(eC.y), h01);
      h10 = gru1(PY(gA.x), PY(gB.x), PY(gC.x), PY(eA.x), PY(eB.x), PY(eC.x), h10);
      h11 = gru1(PY(gA.y), PY(gB.y), PY(gC.y), PY(eA.y), PY(eB.y), PY(eC.y), h11);
#undef PX
#undef PY
      hpk[0][tid] = pk2(h00, h01);
      hpk[1][tid] = pk2(h10, h11);
      // in-wave LDS write->read ordering (wave0 only; pattern verified r8/r9)
      asm volatile("s_waitcnt lgkmcnt(0)" ::: "memory");
      int a = tid & 15, grp = tid >> 4;       // grp: bit0 = row, bit1 = k-half
      int rr = grp & 1, kh = grp >> 1;
      float y = kh ? 0.f : outb_reg;
#pragma unroll
      for (int cc = 0; cc < 8; ++cc) {
        int c = kh*8 + cc;
        uint4 ww = *(const uint4*)&owL[(c*16 + a)*4];
        uint4 hb = LDS4(hpk[rr], c*4);
        y = dot2f(ww.x, hb.x, y); y = dot2f(ww.y, hb.y, y);
        y = dot2f(ww.z, hb.z, y); y = dot2f(ww.w, hb.w, y);
      }
      y += __shfl_xor(y, 32);                 // combine k-halves
      if (tid < 32) {                         // lanes: rr=0 -> 0..15, rr=1 -> 16..31
        float e = __expf(y);                  // |y| small: max-free safe
        float s = e;
#pragma unroll
        for (int off = 8; off; off >>= 1) s += __shfl_xor(s, off);
        float lsf = y - __logf(s);
        if (t == L_-1) dout[(2*bid + rr)*A_ + a] = lsf;
        float pr = __shfl_xor(lsf, 1);
        if (!(a & 1)) inppk[rr][a >> 1] = pk2(lsf, pr);
      }
    }
    __syncthreads();   // S5
  }
}

// =====================================================================
extern "C" void kernel_launch(void* const* d_in, const int* in_sizes, int n_in,
                              void* d_out, int out_size, void* d_ws, size_t ws_size,
                              hipStream_t stream) {
  (void)in_sizes; (void)n_in; (void)out_size; (void)ws_size;
  const float* obs       = (const float*)d_in[0];
  const float* enc_emb_W = (const float*)d_in[1];
  const float* enc_emb_b = (const float*)d_in[2];
  const float* enc_Wih   = (const float*)d_in[3];
  const float* enc_Whh   = (const float*)d_in[4];
  const float* enc_bih   = (const float*)d_in[5];
  const float* enc_bhh   = (const float*)d_in[6];
  const float* dec_emb_W = (const float*)d_in[7];
  const float* dec_emb_b = (const float*)d_in[8];
  const float* attn_W    = (const float*)d_in[9];
  const float* attn_b    = (const float*)d_in[10];
  const float* comb_W    = (const float*)d_in[11];
  const float* comb_b    = (const float*)d_in[12];
  const float* dec_Wih   = (const float*)d_in[13];
  const float* dec_Whh   = (const float*)d_in[14];
  const float* dec_bih   = (const float*)d_in[15];
  const float* dec_bhh   = (const float*)d_in[16];
  const float* out_W     = (const float*)d_in[17];
  const float* out_b     = (const float*)d_in[18];
  char* ws = (char*)d_ws;

  hipLaunchKernelGGL(prep_kernel, dim3(1140), dim3(256), 0, stream,
                     enc_emb_W, enc_emb_b, enc_Wih, enc_bih, dec_emb_W, dec_emb_b,
                     attn_W, attn_b, comb_W, comb_b, dec_Wih, dec_Whh, enc_Whh, out_W, ws);
  hipLaunchKernelGGL(enc_kernel, dim3(256), dim3(512), 0, stream, obs, enc_bhh, ws);
  hipLaunchKernelGGL(dec_kernel, dim3(256), dim3(512), 0, stream,
                     dec_bih, dec_bhh, out_b, ws, (float*)d_out);
}

// Round 11
// 3752.832 us; speedup vs baseline: 4.3488x; 1.0947x over previous
//
#include <hip/hip_runtime.h>
#include <stdint.h>

#define H_  128
#define L_  512
#define B_  512
#define A_  16
#define G3_ 384

// ---------------- workspace layout (bytes) ----------------
#define OFF_M1    0          // f16 [384][128]  enc: Wih@enc_emb_W
#define OFF_WHHE  98304      // f16 [384][128]  enc_Whh
#define OFF_WB    196608     // f16 [512][128]  attn_W[:,128:]
#define OFF_WIH   327680     // f16 [384][128]  dec_Wih
#define OFF_WHH   425984     // f16 [384][128]  dec_Whh
#define OFF_WC2   524288     // f16 [128][128]  comb_W[:,128:]
#define OFF_PA    557056     // f16 [512][16]   Wa@dec_emb_W
#define OFF_PC    573440     // f16 [128][16]   Wc1@dec_emb_W
#define OFF_OUTW  577536     // f16 [16][128]
#define OFF_BGI   581632     // f32 [384]  bih + Wih@enc_emb_b
#define OFF_ZB    583168     // f32 [512]  attn_b + Wa@dec_emb_b
#define OFF_OB    585216     // f32 [128]  comb_b + Wc1@dec_emb_b
#define OFF_ENC   585728     // f16 [512][128]  enc_outs
#define OFF_HN    716800     // f32 [512][128]  final encoder hidden

typedef _Float16 f16_t;
typedef __attribute__((ext_vector_type(2))) _Float16 f16x2_t;

__device__ __forceinline__ float dot2f(uint32_t w, uint32_t a, float acc) {
#if __has_builtin(__builtin_amdgcn_fdot2)
  return __builtin_amdgcn_fdot2(__builtin_bit_cast(f16x2_t, w),
                                __builtin_bit_cast(f16x2_t, a), acc, false);
#else
  f16x2_t x = __builtin_bit_cast(f16x2_t, w);
  f16x2_t y = __builtin_bit_cast(f16x2_t, a);
  return acc + (float)x.x * (float)y.x + (float)x.y * (float)y.y;
#endif
}

__device__ __forceinline__ uint32_t pk2(float lo, float hi) {
#if __has_builtin(__builtin_amdgcn_cvt_pkrtz)
  return __builtin_bit_cast(uint32_t, __builtin_amdgcn_cvt_pkrtz(lo, hi));
#else
  f16x2_t v; v.x = (_Float16)lo; v.y = (_Float16)hi;
  return __builtin_bit_cast(uint32_t, v);
#endif
}

__device__ __forceinline__ float sigm(float x) { return 1.f / (1.f + __expf(-x)); }
__device__ __forceinline__ float tanh_s(float t) { float ex = __expf(2.f * t); return 1.f - 2.f / (ex + 1.f); }
__device__ __forceinline__ float gru1(float ir, float iz, float in_, float hr, float hz, float hn, float h) {
  float rg = sigm(ir + hr);
  float zg = sigm(iz + hz);
  float nn = tanh_s(in_ + rg * hn);
  return (1.f - zg) * nn + zg * h;
}

#define LDS4(arr, idx) (*(const uint4*)&(arr)[(idx)])

// =====================================================================
// prep: weight folds + f16 conversions (unchanged)
// =====================================================================
__global__ void prep_kernel(const float* __restrict__ enc_emb_W, const float* __restrict__ enc_emb_b,
                            const float* __restrict__ enc_Wih, const float* __restrict__ enc_bih,
                            const float* __restrict__ dec_emb_W, const float* __restrict__ dec_emb_b,
                            const float* __restrict__ attn_W, const float* __restrict__ attn_b,
                            const float* __restrict__ comb_W, const float* __restrict__ comb_b,
                            const float* __restrict__ dec_Wih, const float* __restrict__ dec_Whh,
                            const float* __restrict__ enc_Whh, const float* __restrict__ out_W,
                            char* __restrict__ ws) {
  int t = blockIdx.x * 256 + threadIdx.x;
  if (t < 49152) {                       // M1 [384][128]
    int n = t >> 7, d = t & 127; float acc = 0.f;
    for (int h = 0; h < 128; ++h) acc += enc_Wih[n*128+h] * enc_emb_W[h*128+d];
    ((f16_t*)(ws+OFF_M1))[t] = (f16_t)acc; return;
  } t -= 49152;
  if (t < 384) {                         // bias_gi
    float acc = enc_bih[t];
    for (int h = 0; h < 128; ++h) acc += enc_Wih[t*128+h] * enc_emb_b[h];
    ((float*)(ws+OFF_BGI))[t] = acc; return;
  } t -= 384;
  if (t < 8192) {                        // P_a [512][16]
    int l = t >> 4, a = t & 15; float acc = 0.f;
    for (int k = 0; k < 128; ++k) acc += attn_W[l*256+k] * dec_emb_W[k*16+a];
    ((f16_t*)(ws+OFF_PA))[t] = (f16_t)acc; return;
  } t -= 8192;
  if (t < 512) {                         // zbias [512]
    float acc = attn_b[t];
    for (int k = 0; k < 128; ++k) acc += attn_W[t*256+k] * dec_emb_b[k];
    ((float*)(ws+OFF_ZB))[t] = acc; return;
  } t -= 512;
  if (t < 2048) {                        // P_c [128][16]
    int j = t >> 4, a = t & 15; float acc = 0.f;
    for (int k = 0; k < 128; ++k) acc += comb_W[j*256+k] * dec_emb_W[k*16+a];
    ((f16_t*)(ws+OFF_PC))[t] = (f16_t)acc; return;
  } t -= 2048;
  if (t < 128) {                         // obias [128]
    float acc = comb_b[t];
    for (int k = 0; k < 128; ++k) acc += comb_W[t*256+k] * dec_emb_b[k];
    ((float*)(ws+OFF_OB))[t] = acc; return;
  } t -= 128;
  if (t < 65536) {                       // Wb [512][128]
    int l = t >> 7, k = t & 127;
    ((f16_t*)(ws+OFF_WB))[t] = (f16_t)attn_W[l*256+128+k]; return;
  } t -= 65536;
  if (t < 49152) { ((f16_t*)(ws+OFF_WHHE))[t] = (f16_t)enc_Whh[t]; return; } t -= 49152;
  if (t < 49152) { ((f16_t*)(ws+OFF_WIH))[t]  = (f16_t)dec_Wih[t]; return; } t -= 49152;
  if (t < 49152) { ((f16_t*)(ws+OFF_WHH))[t]  = (f16_t)dec_Whh[t]; return; } t -= 49152;
  if (t < 16384) {                       // Wc2 [128][128]
    int j = t >> 7, k = t & 127;
    ((f16_t*)(ws+OFF_WC2))[t] = (f16_t)comb_W[j*256+128+k]; return;
  } t -= 16384;
  if (t < 2048) { ((f16_t*)(ws+OFF_OUTW))[t] = (f16_t)out_W[t]; return; }
}

// =====================================================================
// encoder: 256 blocks x 512 thr, rows (2b, 2b+1), 512 steps
// (round-6 proven config, unchanged)
// =====================================================================
__global__ __launch_bounds__(512, 1) void enc_kernel(const float* __restrict__ obs,
                                                     const float* __restrict__ enc_bhh,
                                                     char* __restrict__ ws) {
  __shared__ __align__(16) uint32_t obspk[2][64];
  __shared__ __align__(16) uint32_t hpk[2][64];
  __shared__ __align__(16) float    gi_s[2][G3_];
  __shared__ __align__(16) float    gh_s[2][G3_];
  __shared__ float bgi_s[G3_], bhh_s[G3_];

  const int tid = threadIdx.x, bid = blockIdx.x;
  const uint32_t* M1u  = (const uint32_t*)(ws + OFF_M1);
  const uint32_t* WHu  = (const uint32_t*)(ws + OFF_WHHE);
  const float*    bgi  = (const float*)(ws + OFF_BGI);
  f16_t* encw = (f16_t*)(ws + OFF_ENC);
  float* hN   = (float*)(ws + OFF_HN);

  uint32_t m1r[64], whr[64];
  if (tid < G3_) {
    const uint4* p1 = (const uint4*)(M1u + tid*64);
    const uint4* p2 = (const uint4*)(WHu + tid*64);
#pragma unroll
    for (int q = 0; q < 16; ++q) {
      uint4 v = p1[q]; m1r[q*4]=v.x; m1r[q*4+1]=v.y; m1r[q*4+2]=v.z; m1r[q*4+3]=v.w;
      uint4 w = p2[q]; whr[q*4]=w.x; whr[q*4+1]=w.y; whr[q*4+2]=w.z; whr[q*4+3]=w.w;
    }
    bgi_s[tid] = bgi[tid]; bhh_s[tid] = enc_bhh[tid];
  }

  const int r = tid >> 7, jj = tid & 127;   // valid for tid<256
  const size_t rowbase = (size_t)(2*bid + r) * L_ * H_ + jj;
  float hreg = 0.f;
  float oA = 0.f;
  if (tid < 256) {
    float o0 = obs[rowbase + 0*H_];
    float op = __shfl_xor(o0, 1);
    if (!(jj & 1)) obspk[r][jj >> 1] = pk2(o0, op);
    oA = obs[rowbase + 1*H_];
  }
  if (tid < 128) hpk[tid>>6][tid&63] = 0u;
  __syncthreads();

#pragma unroll 1
  for (int t = 0; t < L_; ++t) {
    float oB = 0.f;
    if (tid < 256) {
      int tn = (t+2 < L_) ? t+2 : L_-1;
      oB = obs[rowbase + (size_t)tn*H_];
    }
    if (tid < G3_) {
      float g0 = bgi_s[tid], g1 = g0, ga = 0.f, gb = 0.f;
      float e0 = bhh_s[tid], e1 = e0, ea = 0.f, eb = 0.f;
#pragma unroll
      for (int c = 0; c < 16; ++c) {
        uint4 o0 = LDS4(obspk[0], c*4); uint4 o1 = LDS4(obspk[1], c*4);
        uint4 h0 = LDS4(hpk[0],  c*4);  uint4 h1 = LDS4(hpk[1],  c*4);
        g0 = dot2f(m1r[c*4+0], o0.x, g0); g0 = dot2f(m1r[c*4+1], o0.y, g0);
        ga = dot2f(m1r[c*4+2], o0.z, ga); ga = dot2f(m1r[c*4+3], o0.w, ga);
        g1 = dot2f(m1r[c*4+0], o1.x, g1); g1 = dot2f(m1r[c*4+1], o1.y, g1);
        gb = dot2f(m1r[c*4+2], o1.z, gb); gb = dot2f(m1r[c*4+3], o1.w, gb);
        e0 = dot2f(whr[c*4+0], h0.x, e0); e0 = dot2f(whr[c*4+1], h0.y, e0);
        ea = dot2f(whr[c*4+2], h0.z, ea); ea = dot2f(whr[c*4+3], h0.w, ea);
        e1 = dot2f(whr[c*4+0], h1.x, e1); e1 = dot2f(whr[c*4+1], h1.y, e1);
        eb = dot2f(whr[c*4+2], h1.z, eb); eb = dot2f(whr[c*4+3], h1.w, eb);
      }
      gi_s[0][tid] = g0+ga; gi_s[1][tid] = g1+gb;
      gh_s[0][tid] = e0+ea; gh_s[1][tid] = e1+eb;
    }
    __syncthreads();
    if (tid < 256) {
      float ir = gi_s[r][jj], iz = gi_s[r][jj+128], in_ = gi_s[r][jj+256];
      float hr = gh_s[r][jj], hz = gh_s[r][jj+128], hn = gh_s[r][jj+256];
      float h2 = gru1(ir, iz, in_, hr, hz, hn, hreg);
      hreg = h2;
      float hp = __shfl_xor(h2, 1);
      float op = __shfl_xor(oA, 1);
      if (!(jj & 1)) {
        hpk[r][jj >> 1] = pk2(h2, hp);
        obspk[r][jj >> 1] = pk2(oA, op);
      }
      if (bid == 0 && r == 0) encw[t*H_ + jj] = (f16_t)h2;
      oA = oB;
    }
    __syncthreads();
  }
  if (tid < 256) hN[(2*bid + r)*H_ + jj] = hreg;
}

// =====================================================================
// decoder: 256 blocks x 512 thr, rows (2b, 2b+1), 512 steps.
// Round-10 base + (a) P_a/P_c rows in registers (step-invariant),
// (b) I5 split one-row-per-wave (waves 0,1 independent, in-wave
// lgkmcnt ordering each). 5 barriers/step.
// =====================================================================
__global__ __launch_bounds__(512, 1) void dec_kernel(const float* __restrict__ dec_bih,
                                                     const float* __restrict__ dec_bhh,
                                                     const float* __restrict__ out_b,
                                                     char* __restrict__ ws,
                                                     float* __restrict__ dout) {
  __shared__ __align__(16) uint32_t encI[32768];       // 131072B [c][k][q]
  __shared__ __align__(16) uint32_t owL[1024];         // 4096B   out_W [(c*16+a)*4+q]
  __shared__ __align__(16) uint32_t awpk[2][272];      // 2176B   raw exp pairs, +4w pad/64
  __shared__ __align__(16) uint32_t aplpk[2][64];      // 512B
  __shared__ __align__(16) uint32_t gip[G3_];          // 1536B   f16 pair (r0,r1)
  __shared__ __align__(16) uint32_t ghp[G3_];          // 1536B
  __shared__ __align__(16) uint32_t opk[2][64];        // 512B
  __shared__ __align__(16) uint32_t hpk[2][64];        // 512B
  __shared__ __align__(16) uint32_t inppk[2][8];       // 64B
  __shared__ float reds[2][8];                         // 64B

  const int tid = threadIdx.x, bid = blockIdx.x;
  const uint32_t* WBu  = (const uint32_t*)(ws + OFF_WB);
  const uint32_t* WIu  = (const uint32_t*)(ws + OFF_WIH);
  const uint32_t* WHu  = (const uint32_t*)(ws + OFF_WHH);
  const uint32_t* WCu  = (const uint32_t*)(ws + OFF_WC2);
  const uint32_t* PAu  = (const uint32_t*)(ws + OFF_PA);
  const uint32_t* PCu  = (const uint32_t*)(ws + OFF_PC);
  const uint32_t* OWu  = (const uint32_t*)(ws + OFF_OUTW);
  const float*    zb   = (const float*)(ws + OFF_ZB);
  const float*    obg  = (const float*)(ws + OFF_OB);
  const float*    hN   = (const float*)(ws + OFF_HN);

  // ---- register-stationary weights ----
  uint32_t wb[64], wA[64], wB[64];
  {
    const uint4* p = (const uint4*)(WBu + tid*64);
#pragma unroll
    for (int q = 0; q < 16; ++q) { uint4 v = p[q]; wb[q*4]=v.x; wb[q*4+1]=v.y; wb[q*4+2]=v.z; wb[q*4+3]=v.w; }
  }
  if (tid < G3_) {
    const uint4* p = (const uint4*)(WIu + tid*64);
    const uint4* p2 = (const uint4*)(WHu + tid*64);
#pragma unroll
    for (int q = 0; q < 16; ++q) {
      uint4 v = p[q];  wA[q*4]=v.x; wA[q*4+1]=v.y; wA[q*4+2]=v.z; wA[q*4+3]=v.w;
      uint4 w = p2[q]; wB[q*4]=w.x; wB[q*4+1]=w.y; wB[q*4+2]=w.z; wB[q*4+3]=w.w;
    }
  } else {
    const uint4* p = (const uint4*)(WCu + (tid-384)*64);
#pragma unroll
    for (int q = 0; q < 16; ++q) {
      uint4 v = p[q]; wA[q*4]=v.x; wA[q*4+1]=v.y; wA[q*4+2]=v.z; wA[q*4+3]=v.w;
    }
  }
  // ---- step-invariant small rows -> registers ----
  uint32_t paq[8], pcq[8];
  {
    uint4 v0 = *(const uint4*)(PAu + tid*8);
    uint4 v1 = *(const uint4*)(PAu + tid*8 + 4);
    paq[0]=v0.x; paq[1]=v0.y; paq[2]=v0.z; paq[3]=v0.w;
    paq[4]=v1.x; paq[5]=v1.y; paq[6]=v1.z; paq[7]=v1.w;
  }
  if (tid >= G3_) {
    uint4 v0 = *(const uint4*)(PCu + (tid-G3_)*8);
    uint4 v1 = *(const uint4*)(PCu + (tid-G3_)*8 + 4);
    pcq[0]=v0.x; pcq[1]=v0.y; pcq[2]=v0.z; pcq[3]=v0.w;
    pcq[4]=v1.x; pcq[5]=v1.y; pcq[6]=v1.z; pcq[7]=v1.w;
  } else {
#pragma unroll
    for (int q = 0; q < 8; ++q) pcq[q] = 0u;
  }

  // ---- stage enc_outs into interleaved LDS layout ----
  {
    int k = tid & 127, ls = tid >> 7;
    const uint16_t* eg = (const uint16_t*)(ws + OFF_ENC);
    uint16_t* ei = (uint16_t*)encI;
    for (int cc = 0; cc < 16; ++cc) {
      int c = ls*16 + cc;
#pragma unroll
      for (int p = 0; p < 8; ++p) ei[(c*128 + k)*8 + p] = eg[(c*8 + p)*128 + k];
    }
  }
  // ---- stage out_W into LDS ----
  for (int idx = tid; idx < 1024; idx += 512) {
    int qq = idx & 3, rest = idx >> 2, a = rest & 15, c = rest >> 4;
    owL[(c*16 + a)*4 + qq] = OWu[a*64 + c*4 + qq];
  }
  const float zbias    = zb[tid];
  const float bih_reg  = (tid < G3_) ? dec_bih[tid] : 0.f;
  const float bhh_reg  = (tid < G3_) ? dec_bhh[tid] : 0.f;
  const float ob_reg   = (tid >= G3_) ? obg[tid - G3_] : 0.f;
  const float outb_reg = (tid < 128) ? out_b[tid & 15] : 0.f;
  if (tid < 16) inppk[tid>>3][tid&7] = 0u;

  // persistent h: wave w (w = tid>>6, tid<128) holds row w dims (2*lane, 2*lane+1)
  float hA = 0.f, hB = 0.f;
  if (tid < 128) {
    int w = tid >> 6, lane = tid & 63;
    hA = hN[(2*bid + w)*H_ + 2*lane];
    hB = hN[(2*bid + w)*H_ + 2*lane + 1];
    hpk[w][lane] = pk2(hA, hB);
  }
  __syncthreads();

#pragma unroll 1
  for (int t = 0; t < L_; ++t) {
    // ---------- I1: attention logits, raw exp (max-free), wave sums ----------
    {
      uint4 i0 = LDS4(inppk[0], 0), i0b = LDS4(inppk[0], 4);
      uint4 i1 = LDS4(inppk[1], 0), i1b = LDS4(inppk[1], 4);
      float a0 = dot2f(paq[0], i0.x, zbias); a0 = dot2f(paq[1], i0.y, a0);
      a0 = dot2f(paq[2], i0.z, a0);          a0 = dot2f(paq[3], i0.w, a0);
      float b0 = dot2f(paq[4], i0b.x, 0.f);  b0 = dot2f(paq[5], i0b.y, b0);
      b0 = dot2f(paq[6], i0b.z, b0);         b0 = dot2f(paq[7], i0b.w, b0);
      float a1 = dot2f(paq[0], i1.x, zbias); a1 = dot2f(paq[1], i1.y, a1);
      a1 = dot2f(paq[2], i1.z, a1);          a1 = dot2f(paq[3], i1.w, a1);
      float b1 = dot2f(paq[4], i1b.x, 0.f);  b1 = dot2f(paq[5], i1b.y, b1);
      b1 = dot2f(paq[6], i1b.z, b1);         b1 = dot2f(paq[7], i1b.w, b1);
#pragma unroll
      for (int c = 0; c < 16; ++c) {
        uint4 h0 = LDS4(hpk[0], c*4); uint4 h1 = LDS4(hpk[1], c*4);
        a0 = dot2f(wb[c*4+0], h0.x, a0); a0 = dot2f(wb[c*4+1], h0.y, a0);
        b0 = dot2f(wb[c*4+2], h0.z, b0); b0 = dot2f(wb[c*4+3], h0.w, b0);
        a1 = dot2f(wb[c*4+0], h1.x, a1); a1 = dot2f(wb[c*4+1], h1.y, a1);
        b1 = dot2f(wb[c*4+2], h1.z, b1); b1 = dot2f(wb[c*4+3], h1.w, b1);
      }
      // max-free: |z| << 88 so raw expf is safe in f32
      float e0 = __expf(a0 + b0), e1 = __expf(a1 + b1);
      float s0 = e0, s1 = e1;
#pragma unroll
      for (int off = 32; off; off >>= 1) { s0 += __shfl_xor(s0, off); s1 += __shfl_xor(s1, off); }
      int wv = tid >> 6;
      if ((tid & 63) == 0) { reds[0][wv] = s0; reds[1][wv] = s1; }
      float ep0 = __shfl_xor(e0, 1), ep1 = __shfl_xor(e1, 1);
      int awi = (tid >> 1) + ((tid >> 7) << 2);   // +4-word pad per 64 pairs
      if (!(tid & 1)) { awpk[0][awi] = pk2(e0, ep0); awpk[1][awi] = pk2(e1, ep1); }
    }
    __syncthreads();   // S1
    // ---------- I2: normalize + applied = aw @ enc_outs (round-6 mapping) ----------
    {
      int lane = tid & 63, wv3 = tid >> 6;
      int k = wv3*16 + (lane & 15), chunk = lane >> 4;
      float S0 = 0.f, S1 = 0.f;
#pragma unroll
      for (int i = 0; i < 8; ++i) { S0 += reds[0][i]; S1 += reds[1][i]; }
      float is0 = 1.f / S0, is1 = 1.f / S1;
      int eb0 = chunk*8192 + k*4;
      int awb = chunk*68;
      float a00=0.f, a01=0.f, a10=0.f, a11=0.f;
#pragma unroll
      for (int cc = 0; cc < 8; ++cc) {
        uint4 ev = *(const uint4*)&encI[eb0 + cc*512];
        uint4 w0 = *(const uint4*)&awpk[0][awb + cc*4];
        uint4 wq = *(const uint4*)&awpk[1][awb + cc*4];
        a00 = dot2f(ev.x, w0.x, a00); a00 = dot2f(ev.y, w0.y, a00);
        a00 = dot2f(ev.z, w0.z, a00); a00 = dot2f(ev.w, w0.w, a00);
        a10 = dot2f(ev.x, wq.x, a10); a10 = dot2f(ev.y, wq.y, a10);
        a10 = dot2f(ev.z, wq.z, a10); a10 = dot2f(ev.w, wq.w, a10);
      }
#pragma unroll
      for (int cc = 8; cc < 16; ++cc) {
        uint4 ev = *(const uint4*)&encI[eb0 + cc*512];
        uint4 w0 = *(const uint4*)&awpk[0][awb + cc*4];
        uint4 wq = *(const uint4*)&awpk[1][awb + cc*4];
        a01 = dot2f(ev.x, w0.x, a01); a01 = dot2f(ev.y, w0.y, a01);
        a01 = dot2f(ev.z, w0.z, a01); a01 = dot2f(ev.w, w0.w, a01);
        a11 = dot2f(ev.x, wq.x, a11); a11 = dot2f(ev.y, wq.y, a11);
        a11 = dot2f(ev.z, wq.z, a11); a11 = dot2f(ev.w, wq.w, a11);
      }
      float v0 = (a00 + a01) * is0;
      float v1 = (a10 + a11) * is1;
      v0 += __shfl_xor(v0, 16); v0 += __shfl_xor(v0, 32);
      v1 += __shfl_xor(v1, 16); v1 += __shfl_xor(v1, 32);
      float v0p = __shfl_xor(v0, 1), v1p = __shfl_xor(v1, 1);
      if (!(lane & 49)) {
        int kk = k >> 1;
        aplpk[0][kk] = pk2(v0, v0p); aplpk[1][kk] = pk2(v1, v1p);
      }
    }
    __syncthreads();   // S2
    // ---------- I3: {tid>=384: o = relu(...)} || {tid<384: gh} ----------
    if (tid >= G3_) {
      int jj = tid - G3_;
      uint4 i0 = LDS4(inppk[0], 0), i0b = LDS4(inppk[0], 4);
      uint4 i1 = LDS4(inppk[1], 0), i1b = LDS4(inppk[1], 4);
      float o0 = dot2f(pcq[0], i0.x, ob_reg); o0 = dot2f(pcq[1], i0.y, o0);
      o0 = dot2f(pcq[2], i0.z, o0);           o0 = dot2f(pcq[3], i0.w, o0);
      float oa = dot2f(pcq[4], i0b.x, 0.f);   oa = dot2f(pcq[5], i0b.y, oa);
      oa = dot2f(pcq[6], i0b.z, oa);          oa = dot2f(pcq[7], i0b.w, oa);
      float o1 = dot2f(pcq[0], i1.x, ob_reg); o1 = dot2f(pcq[1], i1.y, o1);
      o1 = dot2f(pcq[2], i1.z, o1);           o1 = dot2f(pcq[3], i1.w, o1);
      float obb = dot2f(pcq[4], i1b.x, 0.f);  obb = dot2f(pcq[5], i1b.y, obb);
      obb = dot2f(pcq[6], i1b.z, obb);        obb = dot2f(pcq[7], i1b.w, obb);
#pragma unroll
      for (int c = 0; c < 16; ++c) {
        uint4 p0 = LDS4(aplpk[0], c*4); uint4 p1 = LDS4(aplpk[1], c*4);
        o0 = dot2f(wA[c*4+0], p0.x, o0); o0 = dot2f(wA[c*4+1], p0.y, o0);
        oa = dot2f(wA[c*4+2], p0.z, oa); oa = dot2f(wA[c*4+3], p0.w, oa);
        o1 = dot2f(wA[c*4+0], p1.x, o1); o1 = dot2f(wA[c*4+1], p1.y, o1);
        obb = dot2f(wA[c*4+2], p1.z, obb); obb = dot2f(wA[c*4+3], p1.w, obb);
      }
      o0 = fmaxf(o0 + oa, 0.f); o1 = fmaxf(o1 + obb, 0.f);
      float px0 = __shfl_xor(o0, 1), px1 = __shfl_xor(o1, 1);
      if (!(jj & 1)) { opk[0][jj>>1] = pk2(o0, px0); opk[1][jj>>1] = pk2(o1, px1); }
    } else {
      float e0g = bhh_reg, e1g = e0g, ea = 0.f, eb = 0.f;
#pragma unroll
      for (int c = 0; c < 16; ++c) {
        uint4 h0 = LDS4(hpk[0], c*4); uint4 h1 = LDS4(hpk[1], c*4);
        e0g = dot2f(wB[c*4+0], h0.x, e0g); e0g = dot2f(wB[c*4+1], h0.y, e0g);
        ea  = dot2f(wB[c*4+2], h0.z, ea);  ea  = dot2f(wB[c*4+3], h0.w, ea);
        e1g = dot2f(wB[c*4+0], h1.x, e1g); e1g = dot2f(wB[c*4+1], h1.y, e1g);
        eb  = dot2f(wB[c*4+2], h1.z, eb);  eb  = dot2f(wB[c*4+3], h1.w, eb);
      }
      ghp[tid] = pk2(e0g + ea, e1g + eb);
    }
    __syncthreads();   // S3
    // ---------- I4: gi = o@Wih^T + bih ----------
    if (tid < G3_) {
      float g0 = bih_reg, g1 = g0, ga = 0.f, gb = 0.f;
#pragma unroll
      for (int c = 0; c < 16; ++c) {
        uint4 o0 = LDS4(opk[0], c*4); uint4 o1 = LDS4(opk[1], c*4);
        g0 = dot2f(wA[c*4+0], o0.x, g0); g0 = dot2f(wA[c*4+1], o0.y, g0);
        ga = dot2f(wA[c*4+2], o0.z, ga); ga = dot2f(wA[c*4+3], o0.w, ga);
        g1 = dot2f(wA[c*4+0], o1.x, g1); g1 = dot2f(wA[c*4+1], o1.y, g1);
        gb = dot2f(wA[c*4+2], o1.z, gb); gb = dot2f(wA[c*4+3], o1.w, gb);
      }
      gip[tid] = pk2(g0 + ga, g1 + gb);
    }
    __syncthreads();   // S4
    // ---------- I5 (fused, waves 0&1: one row each): gates -> y -> lsf -> feedback ----------
    if (tid < 128) {
      int w = tid >> 6, lane = tid & 63;
      uint2 gA = *(const uint2*)&gip[2*lane];
      uint2 gB = *(const uint2*)&gip[128 + 2*lane];
      uint2 gC = *(const uint2*)&gip[256 + 2*lane];
      uint2 eA = *(const uint2*)&ghp[2*lane];
      uint2 eB = *(const uint2*)&ghp[128 + 2*lane];
      uint2 eC = *(const uint2*)&ghp[256 + 2*lane];
#define SEL(u) (w ? (float)(__builtin_bit_cast(f16x2_t,(u)).y) : (float)(__builtin_bit_cast(f16x2_t,(u)).x))
      hA = gru1(SEL(gA.x), SEL(gB.x), SEL(gC.x), SEL(eA.x), SEL(eB.x), SEL(eC.x), hA);
      hB = gru1(SEL(gA.y), SEL(gB.y), SEL(gC.y), SEL(eA.y), SEL(eB.y), SEL(eC.y), hB);
#undef SEL
      hpk[w][lane] = pk2(hA, hB);
      // in-wave LDS write->read ordering (each wave touches only hpk[w])
      asm volatile("s_waitcnt lgkmcnt(0)" ::: "memory");
      int a = lane & 15, kh = lane >> 4;      // kh in 0..3: quarter of k-range
      float y = (kh == 0) ? outb_reg : 0.f;
#pragma unroll
      for (int cc = 0; cc < 4; ++cc) {
        int c = kh*4 + cc;
        uint4 ww = *(const uint4*)&owL[(c*16 + a)*4];
        uint4 hb = LDS4(hpk[w], c*4);
        y = dot2f(ww.x, hb.x, y); y = dot2f(ww.y, hb.y, y);
        y = dot2f(ww.z, hb.z, y); y = dot2f(ww.w, hb.w, y);
      }
      y += __shfl_xor(y, 16); y += __shfl_xor(y, 32);   // combine 4 k-quarters
      if (lane < 16) {
        float e = __expf(y);   // |y| small: max-free safe
        float s = e;
#pragma unroll
        for (int off = 8; off; off >>= 1) s += __shfl_xor(s, off);
        float lsf = y - __logf(s);
        if (t == L_-1) dout[(2*bid + w)*A_ + a] = lsf;
        float pr = __shfl_xor(lsf, 1);
        if (!(a & 1)) inppk[w][a >> 1] = pk2(lsf, pr);
      }
    }
    __syncthreads();   // S5
  }
}

// =====================================================================
extern "C" void kernel_launch(void* const* d_in, const int* in_sizes, int n_in,
                              void* d_out, int out_size, void* d_ws, size_t ws_size,
                              hipStream_t stream) {
  (void)in_sizes; (void)n_in; (void)out_size; (void)ws_size;
  const float* obs       = (const float*)d_in[0];
  const float* enc_emb_W = (const float*)d_in[1];
  const float* enc_emb_b = (const float*)d_in[2];
  const float* enc_Wih   = (const float*)d_in[3];
  const float* enc_Whh   = (const float*)d_in[4];
  const float* enc_bih   = (const float*)d_in[5];
  const float* enc_bhh   = (const float*)d_in[6];
  const float* dec_emb_W = (const float*)d_in[7];
  const float* dec_emb_b = (const float*)d_in[8];
  const float* attn_W    = (const float*)d_in[9];
  const float* attn_b    = (const float*)d_in[10];
  const float* comb_W    = (const float*)d_in[11];
  const float* comb_b    = (const float*)d_in[12];
  const float* dec_Wih   = (const float*)d_in[13];
  const float* dec_Whh   = (const float*)d_in[14];
  const float* dec_bih   = (const float*)d_in[15];
  const float* dec_bhh   = (const float*)d_in[16];
  const float* out_W     = (const float*)d_in[17];
  const float* out_b     = (const float*)d_in[18];
  char* ws = (char*)d_ws;

  hipLaunchKernelGGL(prep_kernel, dim3(1140), dim3(256), 0, stream,
                     enc_emb_W, enc_emb_b, enc_Wih, enc_bih, dec_emb_W, dec_emb_b,
                     attn_W, attn_b, comb_W, comb_b, dec_Wih, dec_Whh, enc_Whh, out_W, ws);
  hipLaunchKernelGGL(enc_kernel, dim3(256), dim3(512), 0, stream, obs, enc_bhh, ws);
  hipLaunchKernelGGL(dec_kernel, dim3(256), dim3(512), 0, stream,
                     dec_bih, dec_bhh, out_b, ws, (float*)d_out);
}